// Round 1
// baseline (2994.249 us; speedup 1.0000x reference)
//
#include <hip/hip_runtime.h>
#include <math.h>

#define T 512
#define B 128
#define E 256
#define H 256
#define G 1024   // 4H
#define DA 25
#define HEADS 5
#define V 2080
#define NEGINF (-1e30f)

// ---------------- workspace layout (bytes) ----------------
static constexpr size_t WBT_OFF  = 0;           // [2][128 k2][256 j][4 gate] uint (f16 pair W_hh) 1,048,576
static constexpr size_t WIH_OFF  = 1048576;     // [2][1024 g][256 e] ushort (f16 W_ih)            1,048,576
static constexpr size_t WS1T_OFF = 2097152;     // [25 r][64 l] uint4 (f16 W_s1, lane-major)          25,600
static constexpr size_t PX_OFF   = 2148352;     // [2][64][128][1024] f32     67,108,864
static constexpr size_t HC_OFF   = 69257216;    // [128][512][512] f32       134,217,728
static constexpr size_t HBUF_OFF = 203474944;   // [2][128 b][256 j] f32         262,144
static constexpr size_t CST_OFF  = 203737088;   // [2][128][256] f32 c-state     262,144
static constexpr size_t A_OFF    = 203999232;   // [128][5][512] f32           1,310,720
static constexpr size_t PART_OFF = 205309952;   // [128] f32                         512
static constexpr size_t EMBH_OFF = 205310464;   // [2080][256] ushort (f16 emb) 1,064,960
static constexpr size_t EMBH_END = EMBH_OFF + (size_t)V * E * 2;

typedef _Float16 half2v __attribute__((ext_vector_type(2)));
typedef _Float16 half8_ __attribute__((ext_vector_type(8)));
typedef float    f32x4  __attribute__((ext_vector_type(4)));

__device__ __forceinline__ float sigmoidf_(float x) { return 1.f / (1.f + expf(-x)); }

__device__ __forceinline__ unsigned short f2h_(float f) {   // f32 -> f16 bits
    _Float16 h = (_Float16)f;
    unsigned short u;
    __builtin_memcpy(&u, &h, 2);
    return u;
}

// dot2: acc += w.lo*h.lo + w.hi*h.hi  (f32 accumulate)
__device__ __forceinline__ float fdot2_(unsigned w, half2v h, float acc) {
#if __has_builtin(__builtin_amdgcn_fdot2)
    half2v wv;
    __builtin_memcpy(&wv, &w, 4);
    return __builtin_amdgcn_fdot2(wv, h, acc, false);
#else
    unsigned short lo = (unsigned short)(w & 0xffffu), hi = (unsigned short)(w >> 16);
    _Float16 w0, w1;
    __builtin_memcpy(&w0, &lo, 2);
    __builtin_memcpy(&w1, &hi, 2);
    return fmaf((float)w0, (float)h[0], fmaf((float)w1, (float)h[1], acc));
#endif
}

__device__ __forceinline__ half2v packh2_(float a, float b) {
    half2v h;
    h[0] = (_Float16)a;
    h[1] = (_Float16)b;
    return h;
}

// ---------------- prep: pack W_hh + W_ih + W_s1 (+ emb) to f16 -------------
__global__ __launch_bounds__(256) void prep_kernel(const float* __restrict__ Whf,
                                                   const float* __restrict__ Whb,
                                                   const float* __restrict__ Wif,
                                                   const float* __restrict__ Wib,
                                                   const float* __restrict__ Ws1,
                                                   const float* __restrict__ emb,
                                                   unsigned short* __restrict__ wbt,
                                                   unsigned short* __restrict__ wih,
                                                   unsigned short* __restrict__ ws1p,
                                                   unsigned short* __restrict__ embh) {
    int idx = blockIdx.x * 256 + threadIdx.x;
    if (idx < 2 * G * H) {
        int d = idx >> 18;
        int rem = idx & 262143;
        int r = rem >> 8;                        // gate row 0..1023
        int k = rem & 255;                       // h index
        const float* W = d ? Whb : Whf;
        int gate = r >> 8, j = r & 255;
        int k2 = k >> 1, ke = k & 1;
        wbt[(((size_t)d * 128 + k2) * 256 + j) * 8 + gate * 2 + ke] = f2h_(W[(size_t)r * H + k]);
        const float* Wi = d ? Wib : Wif;
        wih[((size_t)d * G + r) * 256 + k] = f2h_(Wi[(size_t)r * E + k]);
    }
    if (idx < DA * 512) {
        int r = idx / 512, k = idx % 512;
        int kp = k >> 1, ke = k & 1;
        int l = kp & 63, q = kp >> 6;
        ws1p[((r * 64 + l) * 4 + q) * 2 + ke] = f2h_(Ws1[idx]);
    }
    if (embh && idx < V * E) embh[idx] = f2h_(emb[idx]);
}

// ---------------- input projection: MFMA f16 (64s x 64g x K=256 per block) ----
// grid (16 g-blocks, 128 b, 2 d), block 256 = 4 waves; each wave owns a 32x32
// output quadrant as 2x2 mfma_f32_16x16x32_f16 subtiles. A (emb rows) and B
// (W_ih rows, i.e. B^T layout) staged once in LDS with +8 f16 row padding
// (row stride 528 B -> 2-way bank aliasing on b128 frag reads = free).
// Replaces the fdot2 version: per thread 2048 fdot2 + 1024 ds_read_b32
// -> per WAVE 32 ds_read_b128 + 32 MFMA.
__global__ __launch_bounds__(256) void proj_kernel(const int* __restrict__ word_ids,
                                                   const int* __restrict__ lengths,
                                                   const float* __restrict__ emb,
                                                   const unsigned* __restrict__ embh,
                                                   const unsigned* __restrict__ wih,
                                                   const float* __restrict__ bf,
                                                   const float* __restrict__ bb,
                                                   float* __restrict__ pxc, int chunk) {
    int g0 = blockIdx.x * 64;
    int b  = blockIdx.y;
    int d  = blockIdx.z;
    int len = lengths[b];
    int t0 = chunk * 64;
    if (t0 >= len) return;
    const float* bias = d ? bb : bf;

    __shared__ _Float16 A_s[64][264];   // 33792 B, row stride 528 B (16B aligned)
    __shared__ _Float16 B_s[64][264];   // 33792 B

    int tid = threadIdx.x;
    int sr = tid >> 2, sq = tid & 3;    // staging: 4 threads per 512B row, 8 uint4 each

    {
        // A: emb row for s = sr (per-direction index mapping, clamped; rows with
        // t >= len are garbage but never read by lstm)
        int t = t0 + sr;
        int src = d ? max(len - 1 - t, 0) : t;
        int wid = word_ids[b * T + src];
        if (embh) {
            const uint4* ap = (const uint4*)embh + (size_t)wid * 32;
            #pragma unroll
            for (int c = 0; c < 8; c++) {
                uint4 v = ap[sq * 8 + c];
                *(uint4*)&A_s[sr][(sq * 8 + c) * 8] = v;
            }
        } else {
            const float4* ep = (const float4*)(emb + (size_t)wid * E);
            #pragma unroll
            for (int c = 0; c < 8; c++) {
                float4 x0 = ep[(sq * 8 + c) * 2];
                float4 x1 = ep[(sq * 8 + c) * 2 + 1];
                half8_ hv;
                hv[0] = (_Float16)x0.x; hv[1] = (_Float16)x0.y;
                hv[2] = (_Float16)x0.z; hv[3] = (_Float16)x0.w;
                hv[4] = (_Float16)x1.x; hv[5] = (_Float16)x1.y;
                hv[6] = (_Float16)x1.z; hv[7] = (_Float16)x1.w;
                *(half8_*)&A_s[sr][(sq * 8 + c) * 8] = hv;
            }
        }
        // B: W_ih row g0+sr (already f16-packed, [g][e] = B^T layout)
        const uint4* bp = (const uint4*)wih + ((size_t)d * G + g0 + sr) * 32;
        #pragma unroll
        for (int c = 0; c < 8; c++) {
            uint4 v = bp[sq * 8 + c];
            *(uint4*)&B_s[sr][(sq * 8 + c) * 8] = v;
        }
    }
    __syncthreads();

    int lane = tid & 63, wave = tid >> 6;
    int m0 = (wave >> 1) * 32;          // s quadrant base
    int n0 = (wave & 1) * 32;           // g quadrant base
    int lr = lane & 15, lq = lane >> 4;

    f32x4 acc00 = {0.f, 0.f, 0.f, 0.f}, acc01 = {0.f, 0.f, 0.f, 0.f};
    f32x4 acc10 = {0.f, 0.f, 0.f, 0.f}, acc11 = {0.f, 0.f, 0.f, 0.f};

    #pragma unroll
    for (int k0 = 0; k0 < E; k0 += 32) {
        int ka = k0 + lq * 8;
        half8_ af0 = *(const half8_*)&A_s[m0 + lr][ka];
        half8_ af1 = *(const half8_*)&A_s[m0 + 16 + lr][ka];
        half8_ bf0 = *(const half8_*)&B_s[n0 + lr][ka];
        half8_ bf1 = *(const half8_*)&B_s[n0 + 16 + lr][ka];
        acc00 = __builtin_amdgcn_mfma_f32_16x16x32_f16(af0, bf0, acc00, 0, 0, 0);
        acc01 = __builtin_amdgcn_mfma_f32_16x16x32_f16(af0, bf1, acc01, 0, 0, 0);
        acc10 = __builtin_amdgcn_mfma_f32_16x16x32_f16(af1, bf0, acc10, 0, 0, 0);
        acc11 = __builtin_amdgcn_mfma_f32_16x16x32_f16(af1, bf1, acc11, 0, 0, 0);
    }

    // C/D layout (m89-verified): col = lane&15, row = (lane>>4)*4 + reg
    float bia0 = bias[g0 + n0 + lr];
    float bia1 = bias[g0 + n0 + 16 + lr];
    #pragma unroll
    for (int mi = 0; mi < 2; mi++) {
        f32x4 ar0 = mi ? acc10 : acc00;
        f32x4 ar1 = mi ? acc11 : acc01;
        #pragma unroll
        for (int rr = 0; rr < 4; rr++) {
            int s = m0 + mi * 16 + lq * 4 + rr;
            float* dst = pxc + ((size_t)(d * 64 + s) * B + b) * G + g0;
            dst[n0 + lr]      = ar0[rr] + bia0;
            dst[n0 + 16 + lr] = ar1[rr] + bia1;
        }
    }
}

// ---------------- LSTM recurrence: FULL register residency ----------------
// grid (128 b, 2 dir); block 1024 = 16 waves (4/SIMD -> 512 VGPR budget via
// __launch_bounds__(1024,4); 1 block/CU regardless since grid == 256 CUs).
// All 32 weight rows per thread now live in registers (32 x uint4 = 128 VGPR):
// removes the 8 streamed global uint4/thread/timestep (128 KB/CU/timestep of
// L2 traffic, the previous per-timestep critical path) and all LDS weight
// reads. hh broadcasts vectorized: 8 x ds_read_b128 instead of 32 x b32.
__global__ __launch_bounds__(1024, 4) void lstm6_kernel(const int* __restrict__ lengths,
                                                        const unsigned* __restrict__ wbt,
                                                        const float* __restrict__ pxc,
                                                        float* __restrict__ hc_out,
                                                        float* __restrict__ hbuf,
                                                        float* __restrict__ cstate,
                                                        int chunk) {
    int b   = blockIdx.x;
    int d   = blockIdx.y;
    int tid = threadIdx.x;
    int j  = tid & 255;
    int kq = tid >> 8;                 // 0..3 (wave-uniform)

    int len = lengths[b];
    int t0 = chunk * 64;
    if (t0 >= len) return;
    int tend = min(t0 + 64, len);

    __shared__ __align__(16) unsigned hh[128];   // h as f16 pairs
    __shared__ float4 part[3][257];              // kq 1..3 partials

    float* hbufg = hbuf + ((size_t)d * B + b) * 256;

    float c = 0.f, hreg = 0.f;
    if (chunk == 0) {
        if (tid < 128) hh[tid] = 0u;
    } else {
        if (kq == 0) c = cstate[((size_t)d * B + b) * H + j];
        if (tid < 128) {
            half2v hv2 = packh2_(hbufg[2 * tid], hbufg[2 * tid + 1]);
            unsigned hu;
            __builtin_memcpy(&hu, &hv2, 4);
            hh[tid] = hu;
        }
    }

    // thread's W rows: k2 in [kq*32, kq*32+32), column j — all 32 in registers
    const uint4* wp  = (const uint4*)wbt + ((size_t)d * 128 + kq * 32) * 256 + j;
    const float* pxd = pxc + (size_t)d * 64 * B * G;

    uint4 wr[32];
    #pragma unroll
    for (int r = 0; r < 32; r++) wr[r] = wp[(size_t)r * 256];
    __syncthreads();

    const uint4* hh4 = (const uint4*)hh + kq * 8;   // 8 uint4 = this quarter's 32 h-pairs

    for (int t = t0; t < tend; t++) {
        int s = t - t0;
        float p0 = 0.f, p1 = 0.f, p2 = 0.f, p3 = 0.f;
        if (kq == 0) {
            const float* pxs = pxd + ((size_t)s * B + b) * G;
            p0 = pxs[j];
            p1 = pxs[256 + j];
            p2 = pxs[512 + j];
            p3 = pxs[768 + j];
        }
        float a0 = 0.f, a1 = 0.f, a2 = 0.f, a3 = 0.f;

        #define DOT4(WIDX, HU)                              \
            { half2v hx; __builtin_memcpy(&hx, &HU, 4);     \
              a0 = fdot2_(wr[WIDX].x, hx, a0);              \
              a1 = fdot2_(wr[WIDX].y, hx, a1);              \
              a2 = fdot2_(wr[WIDX].z, hx, a2);              \
              a3 = fdot2_(wr[WIDX].w, hx, a3); }
        #pragma unroll
        for (int g = 0; g < 8; g++) {
            uint4 hv = hh4[g];                   // wave-uniform addr -> broadcast
            DOT4(4 * g + 0, hv.x)
            DOT4(4 * g + 1, hv.y)
            DOT4(4 * g + 2, hv.z)
            DOT4(4 * g + 3, hv.w)
        }
        #undef DOT4

        if (kq > 0) part[kq - 1][j] = make_float4(a0, a1, a2, a3);
        __syncthreads();           // barrier 1: partials ready; hh reads done

        if (kq == 0) {
            #pragma unroll
            for (int q = 0; q < 3; q++) {
                float4 qv = part[q][j];
                a0 += qv.x; a1 += qv.y; a2 += qv.z; a3 += qv.w;
            }
            a0 += p0; a1 += p1; a2 += p2; a3 += p3;

            float ig = sigmoidf_(a0), fg = sigmoidf_(a1), og = sigmoidf_(a3);
            c = fg * c + ig * tanhf(a2);
            float h = og * tanhf(c);
            hreg = h;

            float hn = __shfl_down(h, 1);
            if (!(j & 1)) {
                half2v hv2 = packh2_(h, hn);
                unsigned hu;
                __builtin_memcpy(&hu, &hv2, 4);
                hh[j >> 1] = hu;
            }
            int pos = d ? (len - 1 - t) : t;
            hc_out[((size_t)b * T + pos) * (2 * H) + d * H + j] = h;
        }
        __syncthreads();           // barrier 2: hh updated before next reads
    }

    if (kq == 0) {
        cstate[((size_t)d * B + b) * H + j] = c;
        hbufg[j] = hreg;
    }
}

// ---------------- attention logits (masked), f16 dot2, 16-wave blocks ----
__global__ __launch_bounds__(1024) void logits_kernel(const int* __restrict__ lengths,
                                                      const float* __restrict__ hc,
                                                      const uint4* __restrict__ ws1p,
                                                      const float* __restrict__ Ws2,
                                                      float* __restrict__ S) {
    __shared__ uint4 s_w1[DA * 64];    // 25600 B
    __shared__ float s_w2[HEADS * DA];
    int b = blockIdx.y, tt = blockIdx.x;
    int tid = threadIdx.x;
    for (int i = tid; i < DA * 64; i += 1024) s_w1[i] = ws1p[i];
    for (int i = tid; i < HEADS * DA; i += 1024) s_w2[i] = Ws2[i];
    __syncthreads();

    int len = lengths[b];
    int lane = tid & 63, wave = tid >> 6;
    int tbase = tt * 64 + wave * 4;

    if (tbase >= len) {
        if (lane < HEADS) {
            #pragma unroll
            for (int ti = 0; ti < 4; ti++)
                S[((size_t)b * HEADS + lane) * T + tbase + ti] = NEGINF;
        }
        return;
    }

    const float2* hc2 = (const float2*)hc;
    for (int ti = 0; ti < 4; ti++) {
        int t = tbase + ti;
        if (t < len) {
            size_t row = ((size_t)b * T + t) * 256 + lane;
            float2 f0 = hc2[row];
            float2 f1 = hc2[row + 64];
            float2 f2 = hc2[row + 128];
            float2 f3 = hc2[row + 192];
            half2v h0 = packh2_(f0.x, f0.y);
            half2v h1 = packh2_(f1.x, f1.y);
            half2v h2 = packh2_(f2.x, f2.y);
            half2v h3 = packh2_(f3.x, f3.y);
            float y[DA];
            #pragma unroll
            for (int r = 0; r < DA; r++) {
                uint4 w = s_w1[r * 64 + lane];
                float v = fdot2_(w.x, h0, 0.f);
                v = fdot2_(w.y, h1, v);
                v = fdot2_(w.z, h2, v);
                v = fdot2_(w.w, h3, v);
                y[r] = v;
            }
            #pragma unroll
            for (int r = 0; r < DA; r++) {
                float v = y[r];
                for (int off = 32; off; off >>= 1) v += __shfl_xor(v, off, 64);
                y[r] = tanhf(v);
            }
            if (lane < HEADS) {
                float s = 0.f;
                #pragma unroll
                for (int r = 0; r < DA; r++) s += y[r] * s_w2[lane * DA + r];
                S[((size_t)b * HEADS + lane) * T + t] = s;
            }
        } else {
            if (lane < HEADS) S[((size_t)b * HEADS + lane) * T + t] = NEGINF;
        }
    }
}

// ---------------- masked softmax over T, in place ----------------
__global__ __launch_bounds__(256) void softmax_kernel(float* __restrict__ S) {
    int row = blockIdx.x;
    float* p = S + (size_t)row * T;
    int tid = threadIdx.x;
    int lane = tid & 63, wave = tid >> 6;
    __shared__ float rr[4], ss[4];

    float mx = NEGINF;
    #pragma unroll
    for (int i = 0; i < 2; i++) mx = fmaxf(mx, p[tid + i * 256]);
    for (int off = 32; off; off >>= 1) mx = fmaxf(mx, __shfl_xor(mx, off, 64));
    if (lane == 0) rr[wave] = mx;
    __syncthreads();
    mx = fmaxf(fmaxf(rr[0], rr[1]), fmaxf(rr[2], rr[3]));

    float e[2], sum = 0.f;
    #pragma unroll
    for (int i = 0; i < 2; i++) { e[i] = expf(p[tid + i * 256] - mx); sum += e[i]; }
    for (int off = 32; off; off >>= 1) sum += __shfl_xor(sum, off, 64);
    if (lane == 0) ss[wave] = sum;
    __syncthreads();
    sum = ss[0] + ss[1] + ss[2] + ss[3];
    float inv = 1.f / sum;
    #pragma unroll
    for (int i = 0; i < 2; i++) p[tid + i * 256] = e[i] * inv;
}

// ---------------- M = A @ Hc -> d_out, fused penal partials ----------------
__global__ __launch_bounds__(256) void attnM_kernel(const int* __restrict__ lengths,
                                                    const float* __restrict__ A,
                                                    const float* __restrict__ hc,
                                                    float* __restrict__ out,
                                                    float* __restrict__ part) {
    int b = blockIdx.x, tid = threadIdx.x;
    int len = lengths[b];
    const float* Ab  = A + (size_t)b * HEADS * T;
    const float* hcb = hc + (size_t)b * T * (2 * H);
    float acc[HEADS][2];
    #pragma unroll
    for (int h = 0; h < HEADS; h++) { acc[h][0] = 0.f; acc[h][1] = 0.f; }
    float p[10];
    #pragma unroll
    for (int i = 0; i < 10; i++) p[i] = 0.f;

    for (int t = 0; t < len; t++) {
        float v0 = hcb[(size_t)t * (2 * H) + tid];
        float v1 = hcb[(size_t)t * (2 * H) + H + tid];
        float a0 = Ab[t], a1 = Ab[T + t], a2 = Ab[2 * T + t], a3 = Ab[3 * T + t], a4 = Ab[4 * T + t];
        acc[0][0] += a0 * v0; acc[0][1] += a0 * v1;
        acc[1][0] += a1 * v0; acc[1][1] += a1 * v1;
        acc[2][0] += a2 * v0; acc[2][1] += a2 * v1;
        acc[3][0] += a3 * v0; acc[3][1] += a3 * v1;
        acc[4][0] += a4 * v0; acc[4][1] += a4 * v1;
        if ((t & 255) == tid) {
            p[0] += a0 * a1; p[1] += a0 * a2; p[2] += a0 * a3; p[3] += a0 * a4;
            p[4] += a1 * a2; p[5] += a1 * a3; p[6] += a1 * a4;
            p[7] += a2 * a3; p[8] += a2 * a4; p[9] += a3 * a4;
        }
    }
    #pragma unroll
    for (int h = 0; h < HEADS; h++) {
        out[(size_t)b * (HEADS * 2 * H) + h * (2 * H) + tid]     = acc[h][0];
        out[(size_t)b * (HEADS * 2 * H) + h * (2 * H) + H + tid] = acc[h][1];
    }

    __shared__ float red[10][4];
    int lane = tid & 63, wave = tid >> 6;
    #pragma unroll
    for (int i = 0; i < 10; i++) {
        float v = p[i];
        for (int off = 32; off; off >>= 1) v += __shfl_xor(v, off, 64);
        if (lane == 0) red[i][wave] = v;
    }
    __syncthreads();
    if (tid == 0) {
        float s = 0.f;
        #pragma unroll
        for (int i = 0; i < 10; i++) {
            float P = red[i][0] + red[i][1] + red[i][2] + red[i][3];
            s += 2.f * P * P;
        }
        part[b] = s;
    }
}

__global__ __launch_bounds__(128) void final_kernel(const float* __restrict__ part,
                                                    float* __restrict__ out) {
    int tid = threadIdx.x;
    float v = part[tid];
    for (int off = 32; off; off >>= 1) v += __shfl_xor(v, off, 64);
    __shared__ float r2[2];
    if ((tid & 63) == 0) r2[tid >> 6] = v;
    __syncthreads();
    if (tid == 0) out[(size_t)B * HEADS * 2 * H] = (r2[0] + r2[1]) * (1.f / (float)B);
}

// ---------------- host launcher ----------------
extern "C" void kernel_launch(void* const* d_in, const int* in_sizes, int n_in,
                              void* d_out, int out_size, void* d_ws, size_t ws_size,
                              hipStream_t stream) {
    const int*   word_ids = (const int*)d_in[0];
    const int*   lengths  = (const int*)d_in[1];
    const float* emb      = (const float*)d_in[2];
    const float* W_ih_f   = (const float*)d_in[3];
    const float* W_hh_f   = (const float*)d_in[4];
    const float* b_f      = (const float*)d_in[5];
    const float* W_ih_b   = (const float*)d_in[6];
    const float* W_hh_b   = (const float*)d_in[7];
    const float* b_b      = (const float*)d_in[8];
    const float* W_s1     = (const float*)d_in[9];
    const float* W_s2     = (const float*)d_in[10];
    float* out = (float*)d_out;

    char* ws = (char*)d_ws;
    unsigned short* wbt16 = (unsigned short*)(ws + WBT_OFF);
    unsigned*       wbt   = (unsigned*)(ws + WBT_OFF);
    unsigned short* wih16 = (unsigned short*)(ws + WIH_OFF);
    unsigned*       wihu  = (unsigned*)(ws + WIH_OFF);
    unsigned short* ws1p16 = (unsigned short*)(ws + WS1T_OFF);
    const uint4*    ws1p4  = (const uint4*)(ws + WS1T_OFF);
    float* pxc    = (float*)(ws + PX_OFF);
    float* hc     = (float*)(ws + HC_OFF);
    float* hbuf   = (float*)(ws + HBUF_OFF);
    float* cstate = (float*)(ws + CST_OFF);
    float* Abuf   = (float*)(ws + A_OFF);
    float* part   = (float*)(ws + PART_OFF);
    bool have_embh = (ws_size >= EMBH_END);
    unsigned short* embh16 = have_embh ? (unsigned short*)(ws + EMBH_OFF) : nullptr;
    const unsigned* embhu  = have_embh ? (const unsigned*)(ws + EMBH_OFF) : nullptr;

    prep_kernel<<<2080, 256, 0, stream>>>(W_hh_f, W_hh_b, W_ih_f, W_ih_b, W_s1, emb,
                                          wbt16, wih16, ws1p16, embh16);

    for (int c = 0; c < 8; c++) {
        proj_kernel<<<dim3(16, 128, 2), 256, 0, stream>>>(
            word_ids, lengths, emb, embhu, wihu, b_f, b_b, pxc, c);
        lstm6_kernel<<<dim3(128, 2), 1024, 0, stream>>>(
            lengths, wbt, pxc, hc, hbuf, cstate, c);
    }

    logits_kernel<<<dim3(8, 128), 1024, 0, stream>>>(lengths, hc, ws1p4, W_s2, Abuf);
    softmax_kernel<<<B * HEADS, 256, 0, stream>>>(Abuf);
    attnM_kernel<<<B, 256, 0, stream>>>(lengths, Abuf, hc, out, part);
    final_kernel<<<1, 128, 0, stream>>>(part, out);
}

// Round 2
// 1538.559 us; speedup vs baseline: 1.9461x; 1.9461x over previous
//
#include <hip/hip_runtime.h>
#include <math.h>

#define T 512
#define B 128
#define E 256
#define H 256
#define G 1024   // 4H
#define DA 25
#define HEADS 5
#define V 2080
#define NEGINF (-1e30f)

// ---------------- workspace layout (bytes) ----------------
static constexpr size_t WBT_OFF  = 0;           // [2][128 k2][256 j][4 gate] uint (f16 pair W_hh) 1,048,576
static constexpr size_t WIH_OFF  = 1048576;     // [2][1024 g][256 e] ushort (f16 W_ih)            1,048,576
static constexpr size_t WS1T_OFF = 2097152;     // [25 r][64 l] uint4 (f16 W_s1, lane-major)          25,600
static constexpr size_t PX_OFF   = 2148352;     // [2][64][128][1024] f32     67,108,864
static constexpr size_t HC_OFF   = 69257216;    // [128][512][512] f32       134,217,728
static constexpr size_t HBUF_OFF = 203474944;   // [2][128 b][256 j] f32         262,144
static constexpr size_t CST_OFF  = 203737088;   // [2][128][256] f32 c-state     262,144
static constexpr size_t A_OFF    = 203999232;   // [128][5][512] f32           1,310,720
static constexpr size_t PART_OFF = 205309952;   // [128] f32                         512
static constexpr size_t EMBH_OFF = 205310464;   // [2080][256] ushort (f16 emb) 1,064,960
static constexpr size_t EMBH_END = EMBH_OFF + (size_t)V * E * 2;

// ---- lstm6 dynamic LDS layout (bytes) ----
static constexpr unsigned LSTM_LDS_BYTES = 160304;

typedef _Float16 half2v __attribute__((ext_vector_type(2)));
typedef _Float16 half8_ __attribute__((ext_vector_type(8)));
typedef float    f32x4  __attribute__((ext_vector_type(4)));

__device__ __forceinline__ float sigmoidf_(float x) { return 1.f / (1.f + expf(-x)); }

__device__ __forceinline__ unsigned short f2h_(float f) {   // f32 -> f16 bits
    _Float16 h = (_Float16)f;
    unsigned short u;
    __builtin_memcpy(&u, &h, 2);
    return u;
}

// dot2: acc += w.lo*h.lo + w.hi*h.hi  (f32 accumulate)
__device__ __forceinline__ float fdot2_(unsigned w, half2v h, float acc) {
#if __has_builtin(__builtin_amdgcn_fdot2)
    half2v wv;
    __builtin_memcpy(&wv, &w, 4);
    return __builtin_amdgcn_fdot2(wv, h, acc, false);
#else
    unsigned short lo = (unsigned short)(w & 0xffffu), hi = (unsigned short)(w >> 16);
    _Float16 w0, w1;
    __builtin_memcpy(&w0, &lo, 2);
    __builtin_memcpy(&w1, &hi, 2);
    return fmaf((float)w0, (float)h[0], fmaf((float)w1, (float)h[1], acc));
#endif
}

__device__ __forceinline__ half2v packh2_(float a, float b) {
    half2v h;
    h[0] = (_Float16)a;
    h[1] = (_Float16)b;
    return h;
}

// ---------------- prep: pack W_hh + W_ih + W_s1 (+ emb) to f16 -------------
__global__ __launch_bounds__(256) void prep_kernel(const float* __restrict__ Whf,
                                                   const float* __restrict__ Whb,
                                                   const float* __restrict__ Wif,
                                                   const float* __restrict__ Wib,
                                                   const float* __restrict__ Ws1,
                                                   const float* __restrict__ emb,
                                                   unsigned short* __restrict__ wbt,
                                                   unsigned short* __restrict__ wih,
                                                   unsigned short* __restrict__ ws1p,
                                                   unsigned short* __restrict__ embh) {
    int idx = blockIdx.x * 256 + threadIdx.x;
    if (idx < 2 * G * H) {
        int d = idx >> 18;
        int rem = idx & 262143;
        int r = rem >> 8;                        // gate row 0..1023
        int k = rem & 255;                       // h index
        const float* W = d ? Whb : Whf;
        int gate = r >> 8, j = r & 255;
        int k2 = k >> 1, ke = k & 1;
        wbt[(((size_t)d * 128 + k2) * 256 + j) * 8 + gate * 2 + ke] = f2h_(W[(size_t)r * H + k]);
        const float* Wi = d ? Wib : Wif;
        wih[((size_t)d * G + r) * 256 + k] = f2h_(Wi[(size_t)r * E + k]);
    }
    if (idx < DA * 512) {
        int r = idx / 512, k = idx % 512;
        int kp = k >> 1, ke = k & 1;
        int l = kp & 63, q = kp >> 6;
        ws1p[((r * 64 + l) * 4 + q) * 2 + ke] = f2h_(Ws1[idx]);
    }
    if (embh && idx < V * E) embh[idx] = f2h_(emb[idx]);
}

// ---------------- input projection: MFMA f16 (64s x 64g x K=256 per block) ----
// grid (16 g-blocks, 128 b, 2 d), block 256 = 4 waves; each wave owns a 32x32
// output quadrant as 2x2 mfma_f32_16x16x32_f16 subtiles. A (emb rows) and B
// (W_ih rows, i.e. B^T layout) staged once in LDS with +8 f16 row padding
// (row stride 528 B -> 2-way bank aliasing on b128 frag reads = free).
__global__ __launch_bounds__(256) void proj_kernel(const int* __restrict__ word_ids,
                                                   const int* __restrict__ lengths,
                                                   const float* __restrict__ emb,
                                                   const unsigned* __restrict__ embh,
                                                   const unsigned* __restrict__ wih,
                                                   const float* __restrict__ bf,
                                                   const float* __restrict__ bb,
                                                   float* __restrict__ pxc, int chunk) {
    int g0 = blockIdx.x * 64;
    int b  = blockIdx.y;
    int d  = blockIdx.z;
    int len = lengths[b];
    int t0 = chunk * 64;
    if (t0 >= len) return;
    const float* bias = d ? bb : bf;

    __shared__ _Float16 A_s[64][264];   // 33792 B, row stride 528 B (16B aligned)
    __shared__ _Float16 B_s[64][264];   // 33792 B

    int tid = threadIdx.x;
    int sr = tid >> 2, sq = tid & 3;    // staging: 4 threads per 512B row, 8 uint4 each

    {
        int t = t0 + sr;
        int src = d ? max(len - 1 - t, 0) : t;
        int wid = word_ids[b * T + src];
        if (embh) {
            const uint4* ap = (const uint4*)embh + (size_t)wid * 32;
            #pragma unroll
            for (int c = 0; c < 8; c++) {
                uint4 v = ap[sq * 8 + c];
                *(uint4*)&A_s[sr][(sq * 8 + c) * 8] = v;
            }
        } else {
            const float4* ep = (const float4*)(emb + (size_t)wid * E);
            #pragma unroll
            for (int c = 0; c < 8; c++) {
                float4 x0 = ep[(sq * 8 + c) * 2];
                float4 x1 = ep[(sq * 8 + c) * 2 + 1];
                half8_ hv;
                hv[0] = (_Float16)x0.x; hv[1] = (_Float16)x0.y;
                hv[2] = (_Float16)x0.z; hv[3] = (_Float16)x0.w;
                hv[4] = (_Float16)x1.x; hv[5] = (_Float16)x1.y;
                hv[6] = (_Float16)x1.z; hv[7] = (_Float16)x1.w;
                *(half8_*)&A_s[sr][(sq * 8 + c) * 8] = hv;
            }
        }
        const uint4* bp = (const uint4*)wih + ((size_t)d * G + g0 + sr) * 32;
        #pragma unroll
        for (int c = 0; c < 8; c++) {
            uint4 v = bp[sq * 8 + c];
            *(uint4*)&B_s[sr][(sq * 8 + c) * 8] = v;
        }
    }
    __syncthreads();

    int lane = tid & 63, wave = tid >> 6;
    int m0 = (wave >> 1) * 32;          // s quadrant base
    int n0 = (wave & 1) * 32;           // g quadrant base
    int lr = lane & 15, lq = lane >> 4;

    f32x4 acc00 = {0.f, 0.f, 0.f, 0.f}, acc01 = {0.f, 0.f, 0.f, 0.f};
    f32x4 acc10 = {0.f, 0.f, 0.f, 0.f}, acc11 = {0.f, 0.f, 0.f, 0.f};

    #pragma unroll
    for (int k0 = 0; k0 < E; k0 += 32) {
        int ka = k0 + lq * 8;
        half8_ af0 = *(const half8_*)&A_s[m0 + lr][ka];
        half8_ af1 = *(const half8_*)&A_s[m0 + 16 + lr][ka];
        half8_ bf0 = *(const half8_*)&B_s[n0 + lr][ka];
        half8_ bf1 = *(const half8_*)&B_s[n0 + 16 + lr][ka];
        acc00 = __builtin_amdgcn_mfma_f32_16x16x32_f16(af0, bf0, acc00, 0, 0, 0);
        acc01 = __builtin_amdgcn_mfma_f32_16x16x32_f16(af0, bf1, acc01, 0, 0, 0);
        acc10 = __builtin_amdgcn_mfma_f32_16x16x32_f16(af1, bf0, acc10, 0, 0, 0);
        acc11 = __builtin_amdgcn_mfma_f32_16x16x32_f16(af1, bf1, acc11, 0, 0, 0);
    }

    // C/D layout (m89-verified): col = lane&15, row = (lane>>4)*4 + reg
    float bia0 = bias[g0 + n0 + lr];
    float bia1 = bias[g0 + n0 + 16 + lr];
    #pragma unroll
    for (int mi = 0; mi < 2; mi++) {
        f32x4 ar0 = mi ? acc10 : acc00;
        f32x4 ar1 = mi ? acc11 : acc01;
        #pragma unroll
        for (int rr = 0; rr < 4; rr++) {
            int s = m0 + mi * 16 + lq * 4 + rr;
            float* dst = pxc + ((size_t)(d * 64 + s) * B + b) * G + g0;
            dst[n0 + lr]      = ar0[rr] + bia0;
            dst[n0 + 16 + lr] = ar1[rr] + bia1;
        }
    }
}

// ---------------- LSTM recurrence: residency-split W (VERIFIED r18 form) ----
// grid (128 b, 2 dir); block 1024 = 16 waves; 16 waves/CU -> 128 VGPR budget.
// Split sized to that budget: 15 reg rows (60 VGPR) + 9 LDS rows + 8 streamed.
__global__ __launch_bounds__(1024) void lstm6_kernel(const int* __restrict__ lengths,
                                                     const unsigned* __restrict__ wbt,
                                                     const float* __restrict__ pxc,
                                                     float* __restrict__ hc_out,
                                                     float* __restrict__ hbuf,
                                                     float* __restrict__ cstate,
                                                     int chunk) {
    int b   = blockIdx.x;
    int d   = blockIdx.y;
    int tid = threadIdx.x;
    int j  = tid & 255;
    int kq = tid >> 8;                 // 0..3 (wave-uniform)

    int len = lengths[b];
    int t0 = chunk * 64;
    if (t0 >= len) return;
    int tend = min(t0 + 64, len);

    extern __shared__ char smem[];
    unsigned* hh   = (unsigned*)smem;                // [128]
    float4*   part = (float4*)(smem + 512);          // [3][257]
    uint4*    wst  = (uint4*)(smem + 12848);         // [36][256]

    float* hbufg = hbuf + ((size_t)d * B + b) * 256;

    float c = 0.f, hreg = 0.f;
    if (chunk == 0) {
        if (tid < 128) hh[tid] = 0u;
    } else {
        if (kq == 0) c = cstate[((size_t)d * B + b) * H + j];
        if (tid < 128) {
            half2v hv2 = packh2_(hbufg[2 * tid], hbufg[2 * tid + 1]);
            unsigned hu;
            __builtin_memcpy(&hu, &hv2, 4);
            hh[tid] = hu;
        }
    }

    // thread's W rows: k2 in [kq*32, kq*32+32), column j
    const uint4* wp  = (const uint4*)wbt + ((size_t)d * 128 + kq * 32) * 256 + j;
    const float* pxd = pxc + (size_t)d * 64 * B * G;

    // stage k2 0..8 into LDS (thread-private; written+read by same thread)
    #pragma unroll
    for (int r = 0; r < 9; r++)
        wst[(kq * 9 + r) * 256 + j] = wp[(size_t)r * 256];
    // resident k2 9..23 in named registers (15 x uint4 = 60 VGPR raw)
    uint4 wr0  = wp[9 * 256],  wr1  = wp[10 * 256], wr2  = wp[11 * 256];
    uint4 wr3  = wp[12 * 256], wr4  = wp[13 * 256], wr5  = wp[14 * 256];
    uint4 wr6  = wp[15 * 256], wr7  = wp[16 * 256], wr8  = wp[17 * 256];
    uint4 wr9  = wp[18 * 256], wr10 = wp[19 * 256], wr11 = wp[20 * 256];
    uint4 wr12 = wp[21 * 256], wr13 = wp[22 * 256], wr14 = wp[23 * 256];
    __syncthreads();

    for (int t = t0; t < tend; t++) {
        int s = t - t0;
        float p0, p1, p2, p3;
        if (kq == 0) {
            const float* pxs = pxd + ((size_t)s * B + b) * G;
            p0 = pxs[j];
            p1 = pxs[256 + j];
            p2 = pxs[512 + j];
            p3 = pxs[768 + j];
        }
        float a0 = 0.f, a1 = 0.f, a2 = 0.f, a3 = 0.f;

        const unsigned* hhc = hh + kq * 32;

        // streamed k2 24..31 first (loads issue early)
        #pragma unroll
        for (int r = 24; r < 32; r++) {
            uint4 wv = wp[(size_t)r * 256];
            unsigned hu = hhc[r];              // wave-uniform -> broadcast
            half2v hhv;
            __builtin_memcpy(&hhv, &hu, 4);
            a0 = fdot2_(wv.x, hhv, a0);
            a1 = fdot2_(wv.y, hhv, a1);
            a2 = fdot2_(wv.z, hhv, a2);
            a3 = fdot2_(wv.w, hhv, a3);
        }
        // LDS-cached k2 0..8
        #pragma unroll
        for (int r = 0; r < 9; r++) {
            uint4 wv = wst[(kq * 9 + r) * 256 + j];
            unsigned hu = hhc[r];
            half2v hhv;
            __builtin_memcpy(&hhv, &hu, 4);
            a0 = fdot2_(wv.x, hhv, a0);
            a1 = fdot2_(wv.y, hhv, a1);
            a2 = fdot2_(wv.z, hhv, a2);
            a3 = fdot2_(wv.w, hhv, a3);
        }
        // register-resident k2 9..23
        {
            unsigned hu;
            half2v hv;
            #define RES_DOT(WR, IDX)                                   \
                hu = hhc[IDX];                                         \
                __builtin_memcpy(&hv, &hu, 4);                         \
                a0 = fdot2_(WR.x, hv, a0); a1 = fdot2_(WR.y, hv, a1);  \
                a2 = fdot2_(WR.z, hv, a2); a3 = fdot2_(WR.w, hv, a3);
            RES_DOT(wr0, 9)
            RES_DOT(wr1, 10)
            RES_DOT(wr2, 11)
            RES_DOT(wr3, 12)
            RES_DOT(wr4, 13)
            RES_DOT(wr5, 14)
            RES_DOT(wr6, 15)
            RES_DOT(wr7, 16)
            RES_DOT(wr8, 17)
            RES_DOT(wr9, 18)
            RES_DOT(wr10, 19)
            RES_DOT(wr11, 20)
            RES_DOT(wr12, 21)
            RES_DOT(wr13, 22)
            RES_DOT(wr14, 23)
            #undef RES_DOT
        }

        if (kq > 0) part[(kq - 1) * 257 + j] = make_float4(a0, a1, a2, a3);
        __syncthreads();           // barrier 1: partials ready; hh reads done

        if (kq == 0) {
            #pragma unroll
            for (int q = 0; q < 3; q++) {
                float4 qv = part[q * 257 + j];
                a0 += qv.x; a1 += qv.y; a2 += qv.z; a3 += qv.w;
            }
            a0 += p0; a1 += p1; a2 += p2; a3 += p3;

            float ig = sigmoidf_(a0), fg = sigmoidf_(a1), og = sigmoidf_(a3);
            c = fg * c + ig * tanhf(a2);
            float h = og * tanhf(c);
            hreg = h;

            float hn = __shfl_down(h, 1);
            if (!(j & 1)) {
                half2v hv2 = packh2_(h, hn);
                unsigned hu;
                __builtin_memcpy(&hu, &hv2, 4);
                hh[j >> 1] = hu;
            }
            int pos = d ? (len - 1 - t) : t;
            hc_out[((size_t)b * T + pos) * (2 * H) + d * H + j] = h;
        }
        __syncthreads();           // barrier 2: hh updated before next reads
    }

    if (kq == 0) {
        cstate[((size_t)d * B + b) * H + j] = c;
        hbufg[j] = hreg;
    }
}

// ---------------- attention logits (masked), f16 dot2, 16-wave blocks ----
__global__ __launch_bounds__(1024) void logits_kernel(const int* __restrict__ lengths,
                                                      const float* __restrict__ hc,
                                                      const uint4* __restrict__ ws1p,
                                                      const float* __restrict__ Ws2,
                                                      float* __restrict__ S) {
    __shared__ uint4 s_w1[DA * 64];    // 25600 B
    __shared__ float s_w2[HEADS * DA];
    int b = blockIdx.y, tt = blockIdx.x;
    int tid = threadIdx.x;
    for (int i = tid; i < DA * 64; i += 1024) s_w1[i] = ws1p[i];
    for (int i = tid; i < HEADS * DA; i += 1024) s_w2[i] = Ws2[i];
    __syncthreads();

    int len = lengths[b];
    int lane = tid & 63, wave = tid >> 6;
    int tbase = tt * 64 + wave * 4;

    if (tbase >= len) {
        if (lane < HEADS) {
            #pragma unroll
            for (int ti = 0; ti < 4; ti++)
                S[((size_t)b * HEADS + lane) * T + tbase + ti] = NEGINF;
        }
        return;
    }

    const float2* hc2 = (const float2*)hc;
    for (int ti = 0; ti < 4; ti++) {
        int t = tbase + ti;
        if (t < len) {
            size_t row = ((size_t)b * T + t) * 256 + lane;
            float2 f0 = hc2[row];
            float2 f1 = hc2[row + 64];
            float2 f2 = hc2[row + 128];
            float2 f3 = hc2[row + 192];
            half2v h0 = packh2_(f0.x, f0.y);
            half2v h1 = packh2_(f1.x, f1.y);
            half2v h2 = packh2_(f2.x, f2.y);
            half2v h3 = packh2_(f3.x, f3.y);
            float y[DA];
            #pragma unroll
            for (int r = 0; r < DA; r++) {
                uint4 w = s_w1[r * 64 + lane];
                float v = fdot2_(w.x, h0, 0.f);
                v = fdot2_(w.y, h1, v);
                v = fdot2_(w.z, h2, v);
                v = fdot2_(w.w, h3, v);
                y[r] = v;
            }
            #pragma unroll
            for (int r = 0; r < DA; r++) {
                float v = y[r];
                for (int off = 32; off; off >>= 1) v += __shfl_xor(v, off, 64);
                y[r] = tanhf(v);
            }
            if (lane < HEADS) {
                float s = 0.f;
                #pragma unroll
                for (int r = 0; r < DA; r++) s += y[r] * s_w2[lane * DA + r];
                S[((size_t)b * HEADS + lane) * T + t] = s;
            }
        } else {
            if (lane < HEADS) S[((size_t)b * HEADS + lane) * T + t] = NEGINF;
        }
    }
}

// ---------------- masked softmax over T, in place ----------------
__global__ __launch_bounds__(256) void softmax_kernel(float* __restrict__ S) {
    int row = blockIdx.x;
    float* p = S + (size_t)row * T;
    int tid = threadIdx.x;
    int lane = tid & 63, wave = tid >> 6;
    __shared__ float rr[4], ss[4];

    float mx = NEGINF;
    #pragma unroll
    for (int i = 0; i < 2; i++) mx = fmaxf(mx, p[tid + i * 256]);
    for (int off = 32; off; off >>= 1) mx = fmaxf(mx, __shfl_xor(mx, off, 64));
    if (lane == 0) rr[wave] = mx;
    __syncthreads();
    mx = fmaxf(fmaxf(rr[0], rr[1]), fmaxf(rr[2], rr[3]));

    float e[2], sum = 0.f;
    #pragma unroll
    for (int i = 0; i < 2; i++) { e[i] = expf(p[tid + i * 256] - mx); sum += e[i]; }
    for (int off = 32; off; off >>= 1) sum += __shfl_xor(sum, off, 64);
    if (lane == 0) ss[wave] = sum;
    __syncthreads();
    sum = ss[0] + ss[1] + ss[2] + ss[3];
    float inv = 1.f / sum;
    #pragma unroll
    for (int i = 0; i < 2; i++) p[tid + i * 256] = e[i] * inv;
}

// ---------------- M = A @ Hc -> d_out, fused penal partials ----------------
__global__ __launch_bounds__(256) void attnM_kernel(const int* __restrict__ lengths,
                                                    const float* __restrict__ A,
                                                    const float* __restrict__ hc,
                                                    float* __restrict__ out,
                                                    float* __restrict__ part) {
    int b = blockIdx.x, tid = threadIdx.x;
    int len = lengths[b];
    const float* Ab  = A + (size_t)b * HEADS * T;
    const float* hcb = hc + (size_t)b * T * (2 * H);
    float acc[HEADS][2];
    #pragma unroll
    for (int h = 0; h < HEADS; h++) { acc[h][0] = 0.f; acc[h][1] = 0.f; }
    float p[10];
    #pragma unroll
    for (int i = 0; i < 10; i++) p[i] = 0.f;

    for (int t = 0; t < len; t++) {
        float v0 = hcb[(size_t)t * (2 * H) + tid];
        float v1 = hcb[(size_t)t * (2 * H) + H + tid];
        float a0 = Ab[t], a1 = Ab[T + t], a2 = Ab[2 * T + t], a3 = Ab[3 * T + t], a4 = Ab[4 * T + t];
        acc[0][0] += a0 * v0; acc[0][1] += a0 * v1;
        acc[1][0] += a1 * v0; acc[1][1] += a1 * v1;
        acc[2][0] += a2 * v0; acc[2][1] += a2 * v1;
        acc[3][0] += a3 * v0; acc[3][1] += a3 * v1;
        acc[4][0] += a4 * v0; acc[4][1] += a4 * v1;
        if ((t & 255) == tid) {
            p[0] += a0 * a1; p[1] += a0 * a2; p[2] += a0 * a3; p[3] += a0 * a4;
            p[4] += a1 * a2; p[5] += a1 * a3; p[6] += a1 * a4;
            p[7] += a2 * a3; p[8] += a2 * a4; p[9] += a3 * a4;
        }
    }
    #pragma unroll
    for (int h = 0; h < HEADS; h++) {
        out[(size_t)b * (HEADS * 2 * H) + h * (2 * H) + tid]     = acc[h][0];
        out[(size_t)b * (HEADS * 2 * H) + h * (2 * H) + H + tid] = acc[h][1];
    }

    __shared__ float red[10][4];
    int lane = tid & 63, wave = tid >> 6;
    #pragma unroll
    for (int i = 0; i < 10; i++) {
        float v = p[i];
        for (int off = 32; off; off >>= 1) v += __shfl_xor(v, off, 64);
        if (lane == 0) red[i][wave] = v;
    }
    __syncthreads();
    if (tid == 0) {
        float s = 0.f;
        #pragma unroll
        for (int i = 0; i < 10; i++) {
            float P = red[i][0] + red[i][1] + red[i][2] + red[i][3];
            s += 2.f * P * P;
        }
        part[b] = s;
    }
}

__global__ __launch_bounds__(128) void final_kernel(const float* __restrict__ part,
                                                    float* __restrict__ out) {
    int tid = threadIdx.x;
    float v = part[tid];
    for (int off = 32; off; off >>= 1) v += __shfl_xor(v, off, 64);
    __shared__ float r2[2];
    if ((tid & 63) == 0) r2[tid >> 6] = v;
    __syncthreads();
    if (tid == 0) out[(size_t)B * HEADS * 2 * H] = (r2[0] + r2[1]) * (1.f / (float)B);
}

// ---------------- host launcher ----------------
extern "C" void kernel_launch(void* const* d_in, const int* in_sizes, int n_in,
                              void* d_out, int out_size, void* d_ws, size_t ws_size,
                              hipStream_t stream) {
    const int*   word_ids = (const int*)d_in[0];
    const int*   lengths  = (const int*)d_in[1];
    const float* emb      = (const float*)d_in[2];
    const float* W_ih_f   = (const float*)d_in[3];
    const float* W_hh_f   = (const float*)d_in[4];
    const float* b_f      = (const float*)d_in[5];
    const float* W_ih_b   = (const float*)d_in[6];
    const float* W_hh_b   = (const float*)d_in[7];
    const float* b_b      = (const float*)d_in[8];
    const float* W_s1     = (const float*)d_in[9];
    const float* W_s2     = (const float*)d_in[10];
    float* out = (float*)d_out;

    char* ws = (char*)d_ws;
    unsigned short* wbt16 = (unsigned short*)(ws + WBT_OFF);
    unsigned*       wbt   = (unsigned*)(ws + WBT_OFF);
    unsigned short* wih16 = (unsigned short*)(ws + WIH_OFF);
    unsigned*       wihu  = (unsigned*)(ws + WIH_OFF);
    unsigned short* ws1p16 = (unsigned short*)(ws + WS1T_OFF);
    const uint4*    ws1p4  = (const uint4*)(ws + WS1T_OFF);
    float* pxc    = (float*)(ws + PX_OFF);
    float* hc     = (float*)(ws + HC_OFF);
    float* hbuf   = (float*)(ws + HBUF_OFF);
    float* cstate = (float*)(ws + CST_OFF);
    float* Abuf   = (float*)(ws + A_OFF);
    float* part   = (float*)(ws + PART_OFF);
    bool have_embh = (ws_size >= EMBH_END);
    unsigned short* embh16 = have_embh ? (unsigned short*)(ws + EMBH_OFF) : nullptr;
    const unsigned* embhu  = have_embh ? (const unsigned*)(ws + EMBH_OFF) : nullptr;

    prep_kernel<<<2080, 256, 0, stream>>>(W_hh_f, W_hh_b, W_ih_f, W_ih_b, W_s1, emb,
                                          wbt16, wih16, ws1p16, embh16);

    for (int c = 0; c < 8; c++) {
        proj_kernel<<<dim3(16, 128, 2), 256, 0, stream>>>(
            word_ids, lengths, emb, embhu, wihu, b_f, b_b, pxc, c);
        lstm6_kernel<<<dim3(128, 2), 1024, LSTM_LDS_BYTES, stream>>>(
            lengths, wbt, pxc, hc, hbuf, cstate, c);
    }

    logits_kernel<<<dim3(8, 128), 1024, 0, stream>>>(lengths, hc, ws1p4, W_s2, Abuf);
    softmax_kernel<<<B * HEADS, 256, 0, stream>>>(Abuf);
    attnM_kernel<<<B, 256, 0, stream>>>(lengths, Abuf, hc, out, part);
    final_kernel<<<1, 128, 0, stream>>>(part, out);
}

// Round 3
// 1496.734 us; speedup vs baseline: 2.0005x; 1.0279x over previous
//
#include <hip/hip_runtime.h>
#include <math.h>

#define T 512
#define B 128
#define E 256
#define H 256
#define G 1024   // 4H
#define DA 25
#define HEADS 5
#define V 2080
#define NEGINF (-1e30f)

// ---------------- workspace layout (bytes) ----------------
static constexpr size_t WBT_OFF  = 0;           // [2][128 k2][256 j][4 gate] uint (f16 pair W_hh) 1,048,576
static constexpr size_t WIH_OFF  = 1048576;     // [2][1024 g][256 e] ushort (f16 W_ih)            1,048,576
static constexpr size_t WS1M_OFF = 2097152;     // [32 r][512 k] ushort (f16 W_s1, rows 25..31 = 0)   32,768
static constexpr size_t PX_OFF   = 2148352;     // [2][64][128][1024] f32     67,108,864
static constexpr size_t HC_OFF   = 69257216;    // [128][512][512] f32       134,217,728
static constexpr size_t HBUF_OFF = 203474944;   // [2][128 b][256 j] f32         262,144
static constexpr size_t CST_OFF  = 203737088;   // [2][128][256] f32 c-state     262,144
static constexpr size_t A_OFF    = 203999232;   // [128][5][512] f32           1,310,720
static constexpr size_t PART_OFF = 205309952;   // [128] f32                         512
static constexpr size_t EMBH_OFF = 205310464;   // [2080][256] ushort (f16 emb) 1,064,960
static constexpr size_t EMBH_END = EMBH_OFF + (size_t)V * E * 2;

// ---- lstm6 dynamic LDS layout (bytes) ----
static constexpr unsigned LSTM_LDS_BYTES = 160304;

typedef _Float16 half2v __attribute__((ext_vector_type(2)));
typedef _Float16 half8_ __attribute__((ext_vector_type(8)));
typedef float    f32x4  __attribute__((ext_vector_type(4)));

__device__ __forceinline__ float sigmoidf_(float x) { return 1.f / (1.f + expf(-x)); }

__device__ __forceinline__ unsigned short f2h_(float f) {   // f32 -> f16 bits
    _Float16 h = (_Float16)f;
    unsigned short u;
    __builtin_memcpy(&u, &h, 2);
    return u;
}

// dot2: acc += w.lo*h.lo + w.hi*h.hi  (f32 accumulate)
__device__ __forceinline__ float fdot2_(unsigned w, half2v h, float acc) {
#if __has_builtin(__builtin_amdgcn_fdot2)
    half2v wv;
    __builtin_memcpy(&wv, &w, 4);
    return __builtin_amdgcn_fdot2(wv, h, acc, false);
#else
    unsigned short lo = (unsigned short)(w & 0xffffu), hi = (unsigned short)(w >> 16);
    _Float16 w0, w1;
    __builtin_memcpy(&w0, &lo, 2);
    __builtin_memcpy(&w1, &hi, 2);
    return fmaf((float)w0, (float)h[0], fmaf((float)w1, (float)h[1], acc));
#endif
}

__device__ __forceinline__ half2v packh2_(float a, float b) {
    half2v h;
    h[0] = (_Float16)a;
    h[1] = (_Float16)b;
    return h;
}

// ---------------- prep: pack W_hh + W_ih + W_s1 (+ emb) to f16 -------------
__global__ __launch_bounds__(256) void prep_kernel(const float* __restrict__ Whf,
                                                   const float* __restrict__ Whb,
                                                   const float* __restrict__ Wif,
                                                   const float* __restrict__ Wib,
                                                   const float* __restrict__ Ws1,
                                                   const float* __restrict__ emb,
                                                   unsigned short* __restrict__ wbt,
                                                   unsigned short* __restrict__ wih,
                                                   unsigned short* __restrict__ ws1m,
                                                   unsigned short* __restrict__ embh) {
    int idx = blockIdx.x * 256 + threadIdx.x;
    if (idx < 2 * G * H) {
        int d = idx >> 18;
        int rem = idx & 262143;
        int r = rem >> 8;                        // gate row 0..1023
        int k = rem & 255;                       // h index
        const float* W = d ? Whb : Whf;
        int gate = r >> 8, j = r & 255;
        int k2 = k >> 1, ke = k & 1;
        wbt[(((size_t)d * 128 + k2) * 256 + j) * 8 + gate * 2 + ke] = f2h_(W[(size_t)r * H + k]);
        const float* Wi = d ? Wib : Wif;
        wih[((size_t)d * G + r) * 256 + k] = f2h_(Wi[(size_t)r * E + k]);
    }
    if (idx < 32 * 512) {                        // W_s1 as [32][512] f16, rows 25..31 zero
        int r = idx >> 9, k = idx & 511;
        ws1m[idx] = (r < DA) ? f2h_(Ws1[r * 512 + k]) : (unsigned short)0;
    }
    if (embh && idx < V * E) embh[idx] = f2h_(emb[idx]);
}

// ---------------- input projection: MFMA f16 (64s x 64g x K=256 per block) ----
__global__ __launch_bounds__(256) void proj_kernel(const int* __restrict__ word_ids,
                                                   const int* __restrict__ lengths,
                                                   const float* __restrict__ emb,
                                                   const unsigned* __restrict__ embh,
                                                   const unsigned* __restrict__ wih,
                                                   const float* __restrict__ bf,
                                                   const float* __restrict__ bb,
                                                   float* __restrict__ pxc, int chunk) {
    int g0 = blockIdx.x * 64;
    int b  = blockIdx.y;
    int d  = blockIdx.z;
    int len = lengths[b];
    int t0 = chunk * 64;
    if (t0 >= len) return;
    const float* bias = d ? bb : bf;

    __shared__ _Float16 A_s[64][264];   // 33792 B, row stride 528 B (16B aligned)
    __shared__ _Float16 B_s[64][264];   // 33792 B

    int tid = threadIdx.x;
    int sr = tid >> 2, sq = tid & 3;    // staging: 4 threads per 512B row, 8 uint4 each

    {
        int t = t0 + sr;
        int src = d ? max(len - 1 - t, 0) : t;
        int wid = word_ids[b * T + src];
        if (embh) {
            const uint4* ap = (const uint4*)embh + (size_t)wid * 32;
            #pragma unroll
            for (int c = 0; c < 8; c++) {
                uint4 v = ap[sq * 8 + c];
                *(uint4*)&A_s[sr][(sq * 8 + c) * 8] = v;
            }
        } else {
            const float4* ep = (const float4*)(emb + (size_t)wid * E);
            #pragma unroll
            for (int c = 0; c < 8; c++) {
                float4 x0 = ep[(sq * 8 + c) * 2];
                float4 x1 = ep[(sq * 8 + c) * 2 + 1];
                half8_ hv;
                hv[0] = (_Float16)x0.x; hv[1] = (_Float16)x0.y;
                hv[2] = (_Float16)x0.z; hv[3] = (_Float16)x0.w;
                hv[4] = (_Float16)x1.x; hv[5] = (_Float16)x1.y;
                hv[6] = (_Float16)x1.z; hv[7] = (_Float16)x1.w;
                *(half8_*)&A_s[sr][(sq * 8 + c) * 8] = hv;
            }
        }
        const uint4* bp = (const uint4*)wih + ((size_t)d * G + g0 + sr) * 32;
        #pragma unroll
        for (int c = 0; c < 8; c++) {
            uint4 v = bp[sq * 8 + c];
            *(uint4*)&B_s[sr][(sq * 8 + c) * 8] = v;
        }
    }
    __syncthreads();

    int lane = tid & 63, wave = tid >> 6;
    int m0 = (wave >> 1) * 32;          // s quadrant base
    int n0 = (wave & 1) * 32;           // g quadrant base
    int lr = lane & 15, lq = lane >> 4;

    f32x4 acc00 = {0.f, 0.f, 0.f, 0.f}, acc01 = {0.f, 0.f, 0.f, 0.f};
    f32x4 acc10 = {0.f, 0.f, 0.f, 0.f}, acc11 = {0.f, 0.f, 0.f, 0.f};

    #pragma unroll
    for (int k0 = 0; k0 < E; k0 += 32) {
        int ka = k0 + lq * 8;
        half8_ af0 = *(const half8_*)&A_s[m0 + lr][ka];
        half8_ af1 = *(const half8_*)&A_s[m0 + 16 + lr][ka];
        half8_ bf0 = *(const half8_*)&B_s[n0 + lr][ka];
        half8_ bf1 = *(const half8_*)&B_s[n0 + 16 + lr][ka];
        acc00 = __builtin_amdgcn_mfma_f32_16x16x32_f16(af0, bf0, acc00, 0, 0, 0);
        acc01 = __builtin_amdgcn_mfma_f32_16x16x32_f16(af0, bf1, acc01, 0, 0, 0);
        acc10 = __builtin_amdgcn_mfma_f32_16x16x32_f16(af1, bf0, acc10, 0, 0, 0);
        acc11 = __builtin_amdgcn_mfma_f32_16x16x32_f16(af1, bf1, acc11, 0, 0, 0);
    }

    // C/D layout (m89-verified): col = lane&15, row = (lane>>4)*4 + reg
    float bia0 = bias[g0 + n0 + lr];
    float bia1 = bias[g0 + n0 + 16 + lr];
    #pragma unroll
    for (int mi = 0; mi < 2; mi++) {
        f32x4 ar0 = mi ? acc10 : acc00;
        f32x4 ar1 = mi ? acc11 : acc01;
        #pragma unroll
        for (int rr = 0; rr < 4; rr++) {
            int s = m0 + mi * 16 + lq * 4 + rr;
            float* dst = pxc + ((size_t)(d * 64 + s) * B + b) * G + g0;
            dst[n0 + lr]      = ar0[rr] + bia0;
            dst[n0 + 16 + lr] = ar1[rr] + bia1;
        }
    }
}

// ---------------- LSTM recurrence: residency-split W + readlane hh ----------
// grid (128 b, 2 dir); block 1024 = 16 waves; 16 waves/CU -> 128 VGPR budget.
// Split sized to that budget: 15 reg rows (60 VGPR) + 9 LDS rows + 8 streamed.
// hh broadcast via ONE ds_read_b32 per lane + v_readlane (SALU) per row,
// removing 31/32 of the per-step hh LDS-pipe instructions.
__global__ __launch_bounds__(1024) void lstm6_kernel(const int* __restrict__ lengths,
                                                     const unsigned* __restrict__ wbt,
                                                     const float* __restrict__ pxc,
                                                     float* __restrict__ hc_out,
                                                     float* __restrict__ hbuf,
                                                     float* __restrict__ cstate,
                                                     int chunk) {
    int b   = blockIdx.x;
    int d   = blockIdx.y;
    int tid = threadIdx.x;
    int j  = tid & 255;
    int kq = tid >> 8;                 // 0..3 (wave-uniform)

    int len = lengths[b];
    int t0 = chunk * 64;
    if (t0 >= len) return;
    int tend = min(t0 + 64, len);

    extern __shared__ char smem[];
    unsigned* hh   = (unsigned*)smem;                // [128]
    float4*   part = (float4*)(smem + 512);          // [3][257]
    uint4*    wst  = (uint4*)(smem + 12848);         // [36][256]

    float* hbufg = hbuf + ((size_t)d * B + b) * 256;

    float c = 0.f, hreg = 0.f;
    if (chunk == 0) {
        if (tid < 128) hh[tid] = 0u;
    } else {
        if (kq == 0) c = cstate[((size_t)d * B + b) * H + j];
        if (tid < 128) {
            half2v hv2 = packh2_(hbufg[2 * tid], hbufg[2 * tid + 1]);
            unsigned hu;
            __builtin_memcpy(&hu, &hv2, 4);
            hh[tid] = hu;
        }
    }

    // thread's W rows: k2 in [kq*32, kq*32+32), column j
    const uint4* wp  = (const uint4*)wbt + ((size_t)d * 128 + kq * 32) * 256 + j;
    const float* pxd = pxc + (size_t)d * 64 * B * G;

    // stage k2 0..8 into LDS (thread-private; written+read by same thread)
    #pragma unroll
    for (int r = 0; r < 9; r++)
        wst[(kq * 9 + r) * 256 + j] = wp[(size_t)r * 256];
    // resident k2 9..23 in named registers (15 x uint4 = 60 VGPR raw)
    uint4 wr0  = wp[9 * 256],  wr1  = wp[10 * 256], wr2  = wp[11 * 256];
    uint4 wr3  = wp[12 * 256], wr4  = wp[13 * 256], wr5  = wp[14 * 256];
    uint4 wr6  = wp[15 * 256], wr7  = wp[16 * 256], wr8  = wp[17 * 256];
    uint4 wr9  = wp[18 * 256], wr10 = wp[19 * 256], wr11 = wp[20 * 256];
    uint4 wr12 = wp[21 * 256], wr13 = wp[22 * 256], wr14 = wp[23 * 256];
    __syncthreads();

    int hlane = kq * 32 + (tid & 31);   // lanes 32..63 duplicate 0..31 (broadcast pair, free)

    for (int t = t0; t < tend; t++) {
        int s = t - t0;
        float p0, p1, p2, p3;
        if (kq == 0) {
            const float* pxs = pxd + ((size_t)s * B + b) * G;
            p0 = pxs[j];
            p1 = pxs[256 + j];
            p2 = pxs[512 + j];
            p3 = pxs[768 + j];
        }
        float a0 = 0.f, a1 = 0.f, a2 = 0.f, a3 = 0.f;

        // one LDS read/lane: lane l holds hh[kq*32 + (l&31)]; rows broadcast
        // via v_readlane (off the LDS pipe)
        unsigned hlv = hh[hlane];

        #define HROW(IDX) __builtin_amdgcn_readlane(hlv, IDX)

        // streamed k2 24..31 first (loads issue early)
        #pragma unroll
        for (int r = 24; r < 32; r++) {
            uint4 wv = wp[(size_t)r * 256];
            unsigned hu = HROW(r);
            half2v hhv;
            __builtin_memcpy(&hhv, &hu, 4);
            a0 = fdot2_(wv.x, hhv, a0);
            a1 = fdot2_(wv.y, hhv, a1);
            a2 = fdot2_(wv.z, hhv, a2);
            a3 = fdot2_(wv.w, hhv, a3);
        }
        // LDS-cached k2 0..8
        #pragma unroll
        for (int r = 0; r < 9; r++) {
            uint4 wv = wst[(kq * 9 + r) * 256 + j];
            unsigned hu = HROW(r);
            half2v hhv;
            __builtin_memcpy(&hhv, &hu, 4);
            a0 = fdot2_(wv.x, hhv, a0);
            a1 = fdot2_(wv.y, hhv, a1);
            a2 = fdot2_(wv.z, hhv, a2);
            a3 = fdot2_(wv.w, hhv, a3);
        }
        // register-resident k2 9..23
        {
            unsigned hu;
            half2v hv;
            #define RES_DOT(WR, IDX)                                   \
                hu = HROW(IDX);                                        \
                __builtin_memcpy(&hv, &hu, 4);                         \
                a0 = fdot2_(WR.x, hv, a0); a1 = fdot2_(WR.y, hv, a1);  \
                a2 = fdot2_(WR.z, hv, a2); a3 = fdot2_(WR.w, hv, a3);
            RES_DOT(wr0, 9)
            RES_DOT(wr1, 10)
            RES_DOT(wr2, 11)
            RES_DOT(wr3, 12)
            RES_DOT(wr4, 13)
            RES_DOT(wr5, 14)
            RES_DOT(wr6, 15)
            RES_DOT(wr7, 16)
            RES_DOT(wr8, 17)
            RES_DOT(wr9, 18)
            RES_DOT(wr10, 19)
            RES_DOT(wr11, 20)
            RES_DOT(wr12, 21)
            RES_DOT(wr13, 22)
            RES_DOT(wr14, 23)
            #undef RES_DOT
        }
        #undef HROW

        if (kq > 0) part[(kq - 1) * 257 + j] = make_float4(a0, a1, a2, a3);
        __syncthreads();           // barrier 1: partials ready; hh reads done

        if (kq == 0) {
            #pragma unroll
            for (int q = 0; q < 3; q++) {
                float4 qv = part[q * 257 + j];
                a0 += qv.x; a1 += qv.y; a2 += qv.z; a3 += qv.w;
            }
            a0 += p0; a1 += p1; a2 += p2; a3 += p3;

            float ig = sigmoidf_(a0), fg = sigmoidf_(a1), og = sigmoidf_(a3);
            c = fg * c + ig * tanhf(a2);
            float h = og * tanhf(c);
            hreg = h;

            float hn = __shfl_down(h, 1);
            if (!(j & 1)) {
                half2v hv2 = packh2_(h, hn);
                unsigned hu;
                __builtin_memcpy(&hu, &hv2, 4);
                hh[j >> 1] = hu;
            }
            int pos = d ? (len - 1 - t) : t;
            hc_out[((size_t)b * T + pos) * (2 * H) + d * H + j] = h;
        }
        __syncthreads();           // barrier 2: hh updated before next reads
    }

    if (kq == 0) {
        cstate[((size_t)d * B + b) * H + j] = c;
        hbufg[j] = hreg;
    }
}

// ---------------- attention logits via MFMA --------------------------------
// Y[t][r] = tanh(Hc[t] . W_s1[r]) as a [64 x 32] x K=512 f16 MFMA per block,
// then s[t][h] = sum_r Y[t][r] * W_s2[h][r] via per-16-lane weighted butterfly.
// grid (8 tt, 128 b), block 256 = 4 waves; each wave one 16-row m-tile x both
// 16-col n-tiles. Replaces the shfl-heavy fdot2 version (150 LDS-pipe shfl
// per wave per 4 t  ->  ~5 per t).
__global__ __launch_bounds__(256) void logits_kernel(const int* __restrict__ lengths,
                                                     const float* __restrict__ hc,
                                                     const uint4* __restrict__ ws1m,
                                                     const float* __restrict__ Ws2,
                                                     float* __restrict__ S) {
    __shared__ _Float16 A_s[64][520];   // 66560 B (pad: pitch 1040 B ~ bank+4)
    __shared__ _Float16 B_s[32][520];   // 33280 B

    int b = blockIdx.y, tt = blockIdx.x;
    int tid = threadIdx.x;
    int len = lengths[b];
    int t0 = tt * 64;

    int lane = tid & 63, wave = tid >> 6;
    int lr = lane & 15, lq = lane >> 4;
    int m0 = wave * 16;

    if (t0 >= len) {
        // whole tile past length: emit NEGINF for this tile's 64 positions
        if (lr < HEADS) {
            #pragma unroll
            for (int rr = 0; rr < 4; rr++) {
                int t = t0 + m0 + lq * 4 + rr;
                S[((size_t)b * HEADS + lr) * T + t] = NEGINF;
            }
        }
        return;
    }

    // stage B: 32 rows x 512 f16 = 2048 uint4; 8 per thread
    {
        #pragma unroll
        for (int i = 0; i < 8; i++) {
            int u = tid + i * 256;
            int r = u >> 6, c8 = u & 63;
            *(uint4*)&B_s[r][c8 * 8] = ws1m[u];
        }
    }
    // stage A: 64 hc rows -> f16; thread = (row = tid>>2, quarter = tid&3)
    {
        int row = tid >> 2, q = tid & 3;
        int t = t0 + row;                       // t >= len rows are garbage; rows
        const float4* ep = (const float4*)(hc + ((size_t)b * T + t) * 512 + q * 128);
        #pragma unroll
        for (int c = 0; c < 16; c++) {
            float4 x0 = ep[2 * c];
            float4 x1 = ep[2 * c + 1];
            half8_ hv;
            hv[0] = (_Float16)x0.x; hv[1] = (_Float16)x0.y;
            hv[2] = (_Float16)x0.z; hv[3] = (_Float16)x0.w;
            hv[4] = (_Float16)x1.x; hv[5] = (_Float16)x1.y;
            hv[6] = (_Float16)x1.z; hv[7] = (_Float16)x1.w;
            *(half8_*)&A_s[row][q * 128 + c * 8] = hv;
        }
    }
    __syncthreads();

    f32x4 acc0 = {0.f, 0.f, 0.f, 0.f};   // n-tile 0: r = lr
    f32x4 acc1 = {0.f, 0.f, 0.f, 0.f};   // n-tile 1: r = lr + 16
    #pragma unroll
    for (int ks = 0; ks < 16; ks++) {
        int ka = ks * 32 + lq * 8;
        half8_ af  = *(const half8_*)&A_s[m0 + lr][ka];
        half8_ bf0 = *(const half8_*)&B_s[lr][ka];
        half8_ bf1 = *(const half8_*)&B_s[16 + lr][ka];
        acc0 = __builtin_amdgcn_mfma_f32_16x16x32_f16(af, bf0, acc0, 0, 0, 0);
        acc1 = __builtin_amdgcn_mfma_f32_16x16x32_f16(af, bf1, acc1, 0, 0, 0);
    }

    // W_s2 weights for this lane's two r-slots (r=lr, r=lr+16)
    float w2a[HEADS], w2b[HEADS];
    #pragma unroll
    for (int h = 0; h < HEADS; h++) {
        w2a[h] = Ws2[h * DA + lr];                               // lr < 16 < 25
        w2b[h] = (lr + 16 < DA) ? Ws2[h * DA + 16 + lr] : 0.f;   // lr < 9
    }

    // per reg rr: y0,y1 = tanh; weighted butterfly over the 16-lane group
    #pragma unroll
    for (int rr = 0; rr < 4; rr++) {
        float y0 = tanhf(acc0[rr]);
        float y1 = tanhf(acc1[rr]);
        int t = t0 + m0 + lq * 4 + rr;
        float sv[HEADS];
        #pragma unroll
        for (int h = 0; h < HEADS; h++) {
            float v = y0 * w2a[h] + y1 * w2b[h];
            v += __shfl_xor(v, 1, 16);
            v += __shfl_xor(v, 2, 16);
            v += __shfl_xor(v, 4, 16);
            v += __shfl_xor(v, 8, 16);
            sv[h] = v;
        }
        if (lr < HEADS) {
            S[((size_t)b * HEADS + lr) * T + t] = (t < len) ? sv[lr] : NEGINF;
        }
    }
}

// ---------------- masked softmax over T, in place ----------------
__global__ __launch_bounds__(256) void softmax_kernel(float* __restrict__ S) {
    int row = blockIdx.x;
    float* p = S + (size_t)row * T;
    int tid = threadIdx.x;
    int lane = tid & 63, wave = tid >> 6;
    __shared__ float rr[4], ss[4];

    float mx = NEGINF;
    #pragma unroll
    for (int i = 0; i < 2; i++) mx = fmaxf(mx, p[tid + i * 256]);
    for (int off = 32; off; off >>= 1) mx = fmaxf(mx, __shfl_xor(mx, off, 64));
    if (lane == 0) rr[wave] = mx;
    __syncthreads();
    mx = fmaxf(fmaxf(rr[0], rr[1]), fmaxf(rr[2], rr[3]));

    float e[2], sum = 0.f;
    #pragma unroll
    for (int i = 0; i < 2; i++) { e[i] = expf(p[tid + i * 256] - mx); sum += e[i]; }
    for (int off = 32; off; off >>= 1) sum += __shfl_xor(sum, off, 64);
    if (lane == 0) ss[wave] = sum;
    __syncthreads();
    sum = ss[0] + ss[1] + ss[2] + ss[3];
    float inv = 1.f / sum;
    #pragma unroll
    for (int i = 0; i < 2; i++) p[tid + i * 256] = e[i] * inv;
}

// ---------------- M = A @ Hc -> d_out, fused penal partials ----------------
__global__ __launch_bounds__(256) void attnM_kernel(const int* __restrict__ lengths,
                                                    const float* __restrict__ A,
                                                    const float* __restrict__ hc,
                                                    float* __restrict__ out,
                                                    float* __restrict__ part) {
    int b = blockIdx.x, tid = threadIdx.x;
    int len = lengths[b];
    const float* Ab  = A + (size_t)b * HEADS * T;
    const float* hcb = hc + (size_t)b * T * (2 * H);
    float acc[HEADS][2];
    #pragma unroll
    for (int h = 0; h < HEADS; h++) { acc[h][0] = 0.f; acc[h][1] = 0.f; }
    float p[10];
    #pragma unroll
    for (int i = 0; i < 10; i++) p[i] = 0.f;

    for (int t = 0; t < len; t++) {
        float v0 = hcb[(size_t)t * (2 * H) + tid];
        float v1 = hcb[(size_t)t * (2 * H) + H + tid];
        float a0 = Ab[t], a1 = Ab[T + t], a2 = Ab[2 * T + t], a3 = Ab[3 * T + t], a4 = Ab[4 * T + t];
        acc[0][0] += a0 * v0; acc[0][1] += a0 * v1;
        acc[1][0] += a1 * v0; acc[1][1] += a1 * v1;
        acc[2][0] += a2 * v0; acc[2][1] += a2 * v1;
        acc[3][0] += a3 * v0; acc[3][1] += a3 * v1;
        acc[4][0] += a4 * v0; acc[4][1] += a4 * v1;
        if ((t & 255) == tid) {
            p[0] += a0 * a1; p[1] += a0 * a2; p[2] += a0 * a3; p[3] += a0 * a4;
            p[4] += a1 * a2; p[5] += a1 * a3; p[6] += a1 * a4;
            p[7] += a2 * a3; p[8] += a2 * a4; p[9] += a3 * a4;
        }
    }
    #pragma unroll
    for (int h = 0; h < HEADS; h++) {
        out[(size_t)b * (HEADS * 2 * H) + h * (2 * H) + tid]     = acc[h][0];
        out[(size_t)b * (HEADS * 2 * H) + h * (2 * H) + H + tid] = acc[h][1];
    }

    __shared__ float red[10][4];
    int lane = tid & 63, wave = tid >> 6;
    #pragma unroll
    for (int i = 0; i < 10; i++) {
        float v = p[i];
        for (int off = 32; off; off >>= 1) v += __shfl_xor(v, off, 64);
        if (lane == 0) red[i][wave] = v;
    }
    __syncthreads();
    if (tid == 0) {
        float s = 0.f;
        #pragma unroll
        for (int i = 0; i < 10; i++) {
            float P = red[i][0] + red[i][1] + red[i][2] + red[i][3];
            s += 2.f * P * P;
        }
        part[b] = s;
    }
}

__global__ __launch_bounds__(128) void final_kernel(const float* __restrict__ part,
                                                    float* __restrict__ out) {
    int tid = threadIdx.x;
    float v = part[tid];
    for (int off = 32; off; off >>= 1) v += __shfl_xor(v, off, 64);
    __shared__ float r2[2];
    if ((tid & 63) == 0) r2[tid >> 6] = v;
    __syncthreads();
    if (tid == 0) out[(size_t)B * HEADS * 2 * H] = (r2[0] + r2[1]) * (1.f / (float)B);
}

// ---------------- host launcher ----------------
extern "C" void kernel_launch(void* const* d_in, const int* in_sizes, int n_in,
                              void* d_out, int out_size, void* d_ws, size_t ws_size,
                              hipStream_t stream) {
    const int*   word_ids = (const int*)d_in[0];
    const int*   lengths  = (const int*)d_in[1];
    const float* emb      = (const float*)d_in[2];
    const float* W_ih_f   = (const float*)d_in[3];
    const float* W_hh_f   = (const float*)d_in[4];
    const float* b_f      = (const float*)d_in[5];
    const float* W_ih_b   = (const float*)d_in[6];
    const float* W_hh_b   = (const float*)d_in[7];
    const float* b_b      = (const float*)d_in[8];
    const float* W_s1     = (const float*)d_in[9];
    const float* W_s2     = (const float*)d_in[10];
    float* out = (float*)d_out;

    char* ws = (char*)d_ws;
    unsigned short* wbt16 = (unsigned short*)(ws + WBT_OFF);
    unsigned*       wbt   = (unsigned*)(ws + WBT_OFF);
    unsigned short* wih16 = (unsigned short*)(ws + WIH_OFF);
    unsigned*       wihu  = (unsigned*)(ws + WIH_OFF);
    unsigned short* ws1m16 = (unsigned short*)(ws + WS1M_OFF);
    const uint4*    ws1m4  = (const uint4*)(ws + WS1M_OFF);
    float* pxc    = (float*)(ws + PX_OFF);
    float* hc     = (float*)(ws + HC_OFF);
    float* hbuf   = (float*)(ws + HBUF_OFF);
    float* cstate = (float*)(ws + CST_OFF);
    float* Abuf   = (float*)(ws + A_OFF);
    float* part   = (float*)(ws + PART_OFF);
    bool have_embh = (ws_size >= EMBH_END);
    unsigned short* embh16 = have_embh ? (unsigned short*)(ws + EMBH_OFF) : nullptr;
    const unsigned* embhu  = have_embh ? (const unsigned*)(ws + EMBH_OFF) : nullptr;

    prep_kernel<<<2080, 256, 0, stream>>>(W_hh_f, W_hh_b, W_ih_f, W_ih_b, W_s1, emb,
                                          wbt16, wih16, ws1m16, embh16);

    for (int c = 0; c < 8; c++) {
        proj_kernel<<<dim3(16, 128, 2), 256, 0, stream>>>(
            word_ids, lengths, emb, embhu, wihu, b_f, b_b, pxc, c);
        lstm6_kernel<<<dim3(128, 2), 1024, LSTM_LDS_BYTES, stream>>>(
            lengths, wbt, pxc, hc, hbuf, cstate, c);
    }

    logits_kernel<<<dim3(8, 128), 256, 0, stream>>>(lengths, hc, ws1m4, W_s2, Abuf);
    softmax_kernel<<<B * HEADS, 256, 0, stream>>>(Abuf);
    attnM_kernel<<<B, 256, 0, stream>>>(lengths, Abuf, hc, out, part);
    final_kernel<<<1, 128, 0, stream>>>(part, out);
}

// Round 4
// 1303.338 us; speedup vs baseline: 2.2974x; 1.1484x over previous
//
#include <hip/hip_runtime.h>
#include <math.h>

#define T 512
#define B 128
#define E 256
#define H 256
#define G 1024   // 4H
#define DA 25
#define HEADS 5
#define V 2080
#define NEGINF (-1e30f)

// ---------------- workspace layout (bytes) ----------------
static constexpr size_t WBT_OFF  = 0;           // [2][128 k2][256 j][4 gate] uint (f16 pair W_hh) 1,048,576
static constexpr size_t WIH_OFF  = 1048576;     // [2][1024 g][256 e] ushort (f16 W_ih)            1,048,576
static constexpr size_t WS1M_OFF = 2097152;     // [32 r][512 k] ushort (f16 W_s1, rows 25..31 = 0)   32,768
static constexpr size_t PX_OFF   = 2148352;     // [2][64][128][1024] f32     67,108,864
static constexpr size_t HC_OFF   = 69257216;    // [128][512][512] f32       134,217,728
static constexpr size_t HBUF_OFF = 203474944;   // [2][128 b][256 j] f32         262,144
static constexpr size_t CST_OFF  = 203737088;   // [2][128][256] f32 c-state     262,144
static constexpr size_t A_OFF    = 203999232;   // [128][5][512] f32           1,310,720
static constexpr size_t PART_OFF = 205309952;   // [128] f32                         512
static constexpr size_t EMBH_OFF = 205310464;   // [2080][256] ushort (f16 emb) 1,064,960
static constexpr size_t EMBH_END = EMBH_OFF + (size_t)V * E * 2;

// ---- lstm6 dynamic LDS layout (bytes) ----
static constexpr unsigned LSTM_LDS_BYTES = 160304;

typedef _Float16 half2v __attribute__((ext_vector_type(2)));
typedef _Float16 half8_ __attribute__((ext_vector_type(8)));
typedef float    f32x4  __attribute__((ext_vector_type(4)));

#if __has_builtin(__builtin_amdgcn_exp2f)
#define EXP2F_(x) __builtin_amdgcn_exp2f(x)
#else
#define EXP2F_(x) exp2f(x)
#endif
#if __has_builtin(__builtin_amdgcn_rcpf)
#define RCPF_(x) __builtin_amdgcn_rcpf(x)
#else
#define RCPF_(x) (1.0f / (x))
#endif

__device__ __forceinline__ float sigmoidf_(float x) { return 1.f / (1.f + expf(-x)); }

// fast sigmoid/tanh on v_exp/v_rcp; exact +-1 / 0..1 saturation at extremes
__device__ __forceinline__ float sigmoid_fast_(float x) {
    return RCPF_(1.f + EXP2F_(-1.44269504f * x));
}
__device__ __forceinline__ float tanh_fast_(float x) {
    return 1.f - 2.f * RCPF_(1.f + EXP2F_(2.88539008f * x));
}

__device__ __forceinline__ unsigned short f2h_(float f) {   // f32 -> f16 bits
    _Float16 h = (_Float16)f;
    unsigned short u;
    __builtin_memcpy(&u, &h, 2);
    return u;
}

// dot2: acc += w.lo*h.lo + w.hi*h.hi  (f32 accumulate)
__device__ __forceinline__ float fdot2_(unsigned w, half2v h, float acc) {
#if __has_builtin(__builtin_amdgcn_fdot2)
    half2v wv;
    __builtin_memcpy(&wv, &w, 4);
    return __builtin_amdgcn_fdot2(wv, h, acc, false);
#else
    unsigned short lo = (unsigned short)(w & 0xffffu), hi = (unsigned short)(w >> 16);
    _Float16 w0, w1;
    __builtin_memcpy(&w0, &lo, 2);
    __builtin_memcpy(&w1, &hi, 2);
    return fmaf((float)w0, (float)h[0], fmaf((float)w1, (float)h[1], acc));
#endif
}

__device__ __forceinline__ half2v packh2_(float a, float b) {
    half2v h;
    h[0] = (_Float16)a;
    h[1] = (_Float16)b;
    return h;
}

// ---------------- prep: pack W_hh + W_ih + W_s1 (+ emb) to f16 -------------
__global__ __launch_bounds__(256) void prep_kernel(const float* __restrict__ Whf,
                                                   const float* __restrict__ Whb,
                                                   const float* __restrict__ Wif,
                                                   const float* __restrict__ Wib,
                                                   const float* __restrict__ Ws1,
                                                   const float* __restrict__ emb,
                                                   unsigned short* __restrict__ wbt,
                                                   unsigned short* __restrict__ wih,
                                                   unsigned short* __restrict__ ws1m,
                                                   unsigned short* __restrict__ embh) {
    int idx = blockIdx.x * 256 + threadIdx.x;
    if (idx < 2 * G * H) {
        int d = idx >> 18;
        int rem = idx & 262143;
        int r = rem >> 8;                        // gate row 0..1023
        int k = rem & 255;                       // h index
        const float* W = d ? Whb : Whf;
        int gate = r >> 8, j = r & 255;
        int k2 = k >> 1, ke = k & 1;
        wbt[(((size_t)d * 128 + k2) * 256 + j) * 8 + gate * 2 + ke] = f2h_(W[(size_t)r * H + k]);
        const float* Wi = d ? Wib : Wif;
        wih[((size_t)d * G + r) * 256 + k] = f2h_(Wi[(size_t)r * E + k]);
    }
    if (idx < 32 * 512) {                        // W_s1 as [32][512] f16, rows 25..31 zero
        int r = idx >> 9, k = idx & 511;
        ws1m[idx] = (r < DA) ? f2h_(Ws1[r * 512 + k]) : (unsigned short)0;
    }
    if (embh && idx < V * E) embh[idx] = f2h_(emb[idx]);
}

// ---------------- input projection: MFMA f16 (64s x 64g x K=256 per block) ----
__global__ __launch_bounds__(256) void proj_kernel(const int* __restrict__ word_ids,
                                                   const int* __restrict__ lengths,
                                                   const float* __restrict__ emb,
                                                   const unsigned* __restrict__ embh,
                                                   const unsigned* __restrict__ wih,
                                                   const float* __restrict__ bf,
                                                   const float* __restrict__ bb,
                                                   float* __restrict__ pxc, int chunk) {
    int g0 = blockIdx.x * 64;
    int b  = blockIdx.y;
    int d  = blockIdx.z;
    int len = lengths[b];
    int t0 = chunk * 64;
    if (t0 >= len) return;
    const float* bias = d ? bb : bf;

    __shared__ _Float16 A_s[64][264];   // 33792 B, row stride 528 B (16B aligned)
    __shared__ _Float16 B_s[64][264];   // 33792 B

    int tid = threadIdx.x;
    int sr = tid >> 2, sq = tid & 3;    // staging: 4 threads per 512B row, 8 uint4 each

    {
        int t = t0 + sr;
        int src = d ? max(len - 1 - t, 0) : t;
        int wid = word_ids[b * T + src];
        if (embh) {
            const uint4* ap = (const uint4*)embh + (size_t)wid * 32;
            #pragma unroll
            for (int c = 0; c < 8; c++) {
                uint4 v = ap[sq * 8 + c];
                *(uint4*)&A_s[sr][(sq * 8 + c) * 8] = v;
            }
        } else {
            const float4* ep = (const float4*)(emb + (size_t)wid * E);
            #pragma unroll
            for (int c = 0; c < 8; c++) {
                float4 x0 = ep[(sq * 8 + c) * 2];
                float4 x1 = ep[(sq * 8 + c) * 2 + 1];
                half8_ hv;
                hv[0] = (_Float16)x0.x; hv[1] = (_Float16)x0.y;
                hv[2] = (_Float16)x0.z; hv[3] = (_Float16)x0.w;
                hv[4] = (_Float16)x1.x; hv[5] = (_Float16)x1.y;
                hv[6] = (_Float16)x1.z; hv[7] = (_Float16)x1.w;
                *(half8_*)&A_s[sr][(sq * 8 + c) * 8] = hv;
            }
        }
        const uint4* bp = (const uint4*)wih + ((size_t)d * G + g0 + sr) * 32;
        #pragma unroll
        for (int c = 0; c < 8; c++) {
            uint4 v = bp[sq * 8 + c];
            *(uint4*)&B_s[sr][(sq * 8 + c) * 8] = v;
        }
    }
    __syncthreads();

    int lane = tid & 63, wave = tid >> 6;
    int m0 = (wave >> 1) * 32;          // s quadrant base
    int n0 = (wave & 1) * 32;           // g quadrant base
    int lr = lane & 15, lq = lane >> 4;

    f32x4 acc00 = {0.f, 0.f, 0.f, 0.f}, acc01 = {0.f, 0.f, 0.f, 0.f};
    f32x4 acc10 = {0.f, 0.f, 0.f, 0.f}, acc11 = {0.f, 0.f, 0.f, 0.f};

    #pragma unroll
    for (int k0 = 0; k0 < E; k0 += 32) {
        int ka = k0 + lq * 8;
        half8_ af0 = *(const half8_*)&A_s[m0 + lr][ka];
        half8_ af1 = *(const half8_*)&A_s[m0 + 16 + lr][ka];
        half8_ bf0 = *(const half8_*)&B_s[n0 + lr][ka];
        half8_ bf1 = *(const half8_*)&B_s[n0 + 16 + lr][ka];
        acc00 = __builtin_amdgcn_mfma_f32_16x16x32_f16(af0, bf0, acc00, 0, 0, 0);
        acc01 = __builtin_amdgcn_mfma_f32_16x16x32_f16(af0, bf1, acc01, 0, 0, 0);
        acc10 = __builtin_amdgcn_mfma_f32_16x16x32_f16(af1, bf0, acc10, 0, 0, 0);
        acc11 = __builtin_amdgcn_mfma_f32_16x16x32_f16(af1, bf1, acc11, 0, 0, 0);
    }

    // C/D layout (m89-verified): col = lane&15, row = (lane>>4)*4 + reg
    float bia0 = bias[g0 + n0 + lr];
    float bia1 = bias[g0 + n0 + 16 + lr];
    #pragma unroll
    for (int mi = 0; mi < 2; mi++) {
        f32x4 ar0 = mi ? acc10 : acc00;
        f32x4 ar1 = mi ? acc11 : acc01;
        #pragma unroll
        for (int rr = 0; rr < 4; rr++) {
            int s = m0 + mi * 16 + lq * 4 + rr;
            float* dst = pxc + ((size_t)(d * 64 + s) * B + b) * G + g0;
            dst[n0 + lr]      = ar0[rr] + bia0;
            dst[n0 + 16 + lr] = ar1[rr] + bia1;
        }
    }
}

// ---------------- LSTM recurrence: residency-split W, tuned schedule ------
// grid (128 b, 2 dir); block 1024 = 16 waves; LDS 160 KB -> 1 block/CU, so
// request 4 waves/EU -> 128 VGPR budget (without this the compiler targets
// 64 VGPR and banks the 60 resident weight regs in AGPRs with per-use moves).
// Dot-phase order: LDS rows first, streamed rows consumed mid/late so their
// L2 latency hides under fdot2 issue. Epilogue: fast exp2-based activations,
// per-thread ds_write_b16 hh update (no shfl), hc_out store deferred to the
// next step's dot phase.
__global__ __launch_bounds__(1024, 4) void lstm6_kernel(const int* __restrict__ lengths,
                                                        const unsigned* __restrict__ wbt,
                                                        const float* __restrict__ pxc,
                                                        float* __restrict__ hc_out,
                                                        float* __restrict__ hbuf,
                                                        float* __restrict__ cstate,
                                                        int chunk) {
    int b   = blockIdx.x;
    int d   = blockIdx.y;
    int tid = threadIdx.x;
    int j  = tid & 255;
    int kq = tid >> 8;                 // 0..3 (wave-uniform)

    int len = lengths[b];
    int t0 = chunk * 64;
    if (t0 >= len) return;
    int tend = min(t0 + 64, len);

    extern __shared__ char smem[];
    unsigned* hh   = (unsigned*)smem;                // [128]
    float4*   part = (float4*)(smem + 512);          // [3][257]
    uint4*    wst  = (uint4*)(smem + 12848);         // [36][256]
    unsigned short* hh16 = (unsigned short*)smem;    // alias: h as f16[256]

    float* hbufg = hbuf + ((size_t)d * B + b) * 256;

    float c = 0.f, hreg = 0.f;
    if (chunk == 0) {
        if (tid < 128) hh[tid] = 0u;
    } else {
        if (kq == 0) c = cstate[((size_t)d * B + b) * H + j];
        if (tid < 128) {
            half2v hv2 = packh2_(hbufg[2 * tid], hbufg[2 * tid + 1]);
            unsigned hu;
            __builtin_memcpy(&hu, &hv2, 4);
            hh[tid] = hu;
        }
    }

    // thread's W rows: k2 in [kq*32, kq*32+32), column j
    const uint4* wp  = (const uint4*)wbt + ((size_t)d * 128 + kq * 32) * 256 + j;
    const float* pxd = pxc + (size_t)d * 64 * B * G;

    // stage k2 0..8 into LDS (thread-private; written+read by same thread)
    #pragma unroll
    for (int r = 0; r < 9; r++)
        wst[(kq * 9 + r) * 256 + j] = wp[(size_t)r * 256];
    // resident k2 9..23 in named registers (15 x uint4 = 60 VGPR raw)
    uint4 wr0  = wp[9 * 256],  wr1  = wp[10 * 256], wr2  = wp[11 * 256];
    uint4 wr3  = wp[12 * 256], wr4  = wp[13 * 256], wr5  = wp[14 * 256];
    uint4 wr6  = wp[15 * 256], wr7  = wp[16 * 256], wr8  = wp[17 * 256];
    uint4 wr9  = wp[18 * 256], wr10 = wp[19 * 256], wr11 = wp[20 * 256];
    uint4 wr12 = wp[21 * 256], wr13 = wp[22 * 256], wr14 = wp[23 * 256];
    __syncthreads();

    int hlane = kq * 32 + (tid & 31);   // lanes 32..63 duplicate 0..31 (broadcast pair, free)
    int pendpos = -1;

    for (int t = t0; t < tend; t++) {
        int s = t - t0;

        // deferred hc_out store for step t-1: drains during this dot phase
        if (kq == 0 && pendpos >= 0)
            hc_out[((size_t)b * T + pendpos) * (2 * H) + d * H + j] = hreg;

        float p0, p1, p2, p3;
        if (kq == 0) {
            const float* pxs = pxd + ((size_t)s * B + b) * G;
            p0 = pxs[j];
            p1 = pxs[256 + j];
            p2 = pxs[512 + j];
            p3 = pxs[768 + j];
        }

        unsigned hlv = hh[hlane];       // one LDS b32/lane; rows via readlane
        // issue streamed group 0 (rows 24..27) early
        uint4 wv0 = wp[24 * 256], wv1 = wp[25 * 256], wv2 = wp[26 * 256], wv3 = wp[27 * 256];

        float a0 = 0.f, a1 = 0.f, a2 = 0.f, a3 = 0.f;

        #define HROW(IDX) __builtin_amdgcn_readlane(hlv, IDX)
        #define DOT4(WV, IDX)                                          \
            { unsigned hu = HROW(IDX); half2v hx;                      \
              __builtin_memcpy(&hx, &hu, 4);                           \
              a0 = fdot2_(WV.x, hx, a0); a1 = fdot2_(WV.y, hx, a1);    \
              a2 = fdot2_(WV.z, hx, a2); a3 = fdot2_(WV.w, hx, a3); }

        // LDS-cached k2 0..8 (covers group-0 L2 latency)
        #pragma unroll
        for (int r = 0; r < 9; r++) {
            uint4 wv = wst[(kq * 9 + r) * 256 + j];
            DOT4(wv, r)
        }
        // consume streamed group 0
        DOT4(wv0, 24) DOT4(wv1, 25) DOT4(wv2, 26) DOT4(wv3, 27)
        // issue streamed group 1 (rows 28..31)
        uint4 wv4 = wp[28 * 256], wv5 = wp[29 * 256], wv6 = wp[30 * 256], wv7 = wp[31 * 256];
        // register-resident k2 9..23 (covers group-1 L2 latency)
        DOT4(wr0, 9)  DOT4(wr1, 10)  DOT4(wr2, 11)  DOT4(wr3, 12)
        DOT4(wr4, 13) DOT4(wr5, 14)  DOT4(wr6, 15)  DOT4(wr7, 16)
        DOT4(wr8, 17) DOT4(wr9, 18)  DOT4(wr10, 19) DOT4(wr11, 20)
        DOT4(wr12, 21) DOT4(wr13, 22) DOT4(wr14, 23)
        // consume streamed group 1
        DOT4(wv4, 28) DOT4(wv5, 29) DOT4(wv6, 30) DOT4(wv7, 31)
        #undef DOT4
        #undef HROW

        if (kq > 0) part[(kq - 1) * 257 + j] = make_float4(a0, a1, a2, a3);
        __syncthreads();           // barrier 1: partials ready; hh reads done

        if (kq == 0) {
            __builtin_amdgcn_s_setprio(1);
            #pragma unroll
            for (int q = 0; q < 3; q++) {
                float4 qv = part[q * 257 + j];
                a0 += qv.x; a1 += qv.y; a2 += qv.z; a3 += qv.w;
            }
            a0 += p0; a1 += p1; a2 += p2; a3 += p3;

            float ig = sigmoid_fast_(a0), fg = sigmoid_fast_(a1), og = sigmoid_fast_(a3);
            c = fg * c + ig * tanh_fast_(a2);
            float h = og * tanh_fast_(c);
            hreg = h;
            hh16[j] = f2h_(h);      // per-thread b16 write (no shfl)
            pendpos = d ? (len - 1 - t) : t;
            __builtin_amdgcn_s_setprio(0);
        }
        __syncthreads();           // barrier 2: hh updated before next reads
    }

    if (kq == 0) {
        if (pendpos >= 0)
            hc_out[((size_t)b * T + pendpos) * (2 * H) + d * H + j] = hreg;
        cstate[((size_t)d * B + b) * H + j] = c;
        hbufg[j] = hreg;
    }
}

// ---------------- attention logits via MFMA --------------------------------
__global__ __launch_bounds__(256) void logits_kernel(const int* __restrict__ lengths,
                                                     const float* __restrict__ hc,
                                                     const uint4* __restrict__ ws1m,
                                                     const float* __restrict__ Ws2,
                                                     float* __restrict__ S) {
    __shared__ _Float16 A_s[64][520];   // 66560 B (pad: pitch 1040 B ~ bank+4)
    __shared__ _Float16 B_s[32][520];   // 33280 B

    int b = blockIdx.y, tt = blockIdx.x;
    int tid = threadIdx.x;
    int len = lengths[b];
    int t0 = tt * 64;

    int lane = tid & 63, wave = tid >> 6;
    int lr = lane & 15, lq = lane >> 4;
    int m0 = wave * 16;

    if (t0 >= len) {
        if (lr < HEADS) {
            #pragma unroll
            for (int rr = 0; rr < 4; rr++) {
                int t = t0 + m0 + lq * 4 + rr;
                S[((size_t)b * HEADS + lr) * T + t] = NEGINF;
            }
        }
        return;
    }

    // stage B: 32 rows x 512 f16 = 2048 uint4; 8 per thread
    {
        #pragma unroll
        for (int i = 0; i < 8; i++) {
            int u = tid + i * 256;
            int r = u >> 6, c8 = u & 63;
            *(uint4*)&B_s[r][c8 * 8] = ws1m[u];
        }
    }
    // stage A: 64 hc rows -> f16; thread = (row = tid>>2, quarter = tid&3)
    {
        int row = tid >> 2, q = tid & 3;
        int t = t0 + row;
        const float4* ep = (const float4*)(hc + ((size_t)b * T + t) * 512 + q * 128);
        #pragma unroll
        for (int c = 0; c < 16; c++) {
            float4 x0 = ep[2 * c];
            float4 x1 = ep[2 * c + 1];
            half8_ hv;
            hv[0] = (_Float16)x0.x; hv[1] = (_Float16)x0.y;
            hv[2] = (_Float16)x0.z; hv[3] = (_Float16)x0.w;
            hv[4] = (_Float16)x1.x; hv[5] = (_Float16)x1.y;
            hv[6] = (_Float16)x1.z; hv[7] = (_Float16)x1.w;
            *(half8_*)&A_s[row][q * 128 + c * 8] = hv;
        }
    }
    __syncthreads();

    f32x4 acc0 = {0.f, 0.f, 0.f, 0.f};   // n-tile 0: r = lr
    f32x4 acc1 = {0.f, 0.f, 0.f, 0.f};   // n-tile 1: r = lr + 16
    #pragma unroll
    for (int ks = 0; ks < 16; ks++) {
        int ka = ks * 32 + lq * 8;
        half8_ af  = *(const half8_*)&A_s[m0 + lr][ka];
        half8_ bf0 = *(const half8_*)&B_s[lr][ka];
        half8_ bf1 = *(const half8_*)&B_s[16 + lr][ka];
        acc0 = __builtin_amdgcn_mfma_f32_16x16x32_f16(af, bf0, acc0, 0, 0, 0);
        acc1 = __builtin_amdgcn_mfma_f32_16x16x32_f16(af, bf1, acc1, 0, 0, 0);
    }

    // W_s2 weights for this lane's two r-slots (r=lr, r=lr+16)
    float w2a[HEADS], w2b[HEADS];
    #pragma unroll
    for (int h = 0; h < HEADS; h++) {
        w2a[h] = Ws2[h * DA + lr];
        w2b[h] = (lr + 16 < DA) ? Ws2[h * DA + 16 + lr] : 0.f;
    }

    #pragma unroll
    for (int rr = 0; rr < 4; rr++) {
        float y0 = tanhf(acc0[rr]);
        float y1 = tanhf(acc1[rr]);
        int t = t0 + m0 + lq * 4 + rr;
        float sv[HEADS];
        #pragma unroll
        for (int h = 0; h < HEADS; h++) {
            float v = y0 * w2a[h] + y1 * w2b[h];
            v += __shfl_xor(v, 1, 16);
            v += __shfl_xor(v, 2, 16);
            v += __shfl_xor(v, 4, 16);
            v += __shfl_xor(v, 8, 16);
            sv[h] = v;
        }
        if (lr < HEADS) {
            S[((size_t)b * HEADS + lr) * T + t] = (t < len) ? sv[lr] : NEGINF;
        }
    }
}

// ---------------- masked softmax over T, in place ----------------
__global__ __launch_bounds__(256) void softmax_kernel(float* __restrict__ S) {
    int row = blockIdx.x;
    float* p = S + (size_t)row * T;
    int tid = threadIdx.x;
    int lane = tid & 63, wave = tid >> 6;
    __shared__ float rr[4], ss[4];

    float mx = NEGINF;
    #pragma unroll
    for (int i = 0; i < 2; i++) mx = fmaxf(mx, p[tid + i * 256]);
    for (int off = 32; off; off >>= 1) mx = fmaxf(mx, __shfl_xor(mx, off, 64));
    if (lane == 0) rr[wave] = mx;
    __syncthreads();
    mx = fmaxf(fmaxf(rr[0], rr[1]), fmaxf(rr[2], rr[3]));

    float e[2], sum = 0.f;
    #pragma unroll
    for (int i = 0; i < 2; i++) { e[i] = expf(p[tid + i * 256] - mx); sum += e[i]; }
    for (int off = 32; off; off >>= 1) sum += __shfl_xor(sum, off, 64);
    if (lane == 0) ss[wave] = sum;
    __syncthreads();
    sum = ss[0] + ss[1] + ss[2] + ss[3];
    float inv = 1.f / sum;
    #pragma unroll
    for (int i = 0; i < 2; i++) p[tid + i * 256] = e[i] * inv;
}

// ---------------- M = A @ Hc -> d_out, fused penal partials ----------------
__global__ __launch_bounds__(256) void attnM_kernel(const int* __restrict__ lengths,
                                                    const float* __restrict__ A,
                                                    const float* __restrict__ hc,
                                                    float* __restrict__ out,
                                                    float* __restrict__ part) {
    int b = blockIdx.x, tid = threadIdx.x;
    int len = lengths[b];
    const float* Ab  = A + (size_t)b * HEADS * T;
    const float* hcb = hc + (size_t)b * T * (2 * H);
    float acc[HEADS][2];
    #pragma unroll
    for (int h = 0; h < HEADS; h++) { acc[h][0] = 0.f; acc[h][1] = 0.f; }
    float p[10];
    #pragma unroll
    for (int i = 0; i < 10; i++) p[i] = 0.f;

    for (int t = 0; t < len; t++) {
        float v0 = hcb[(size_t)t * (2 * H) + tid];
        float v1 = hcb[(size_t)t * (2 * H) + H + tid];
        float a0 = Ab[t], a1 = Ab[T + t], a2 = Ab[2 * T + t], a3 = Ab[3 * T + t], a4 = Ab[4 * T + t];
        acc[0][0] += a0 * v0; acc[0][1] += a0 * v1;
        acc[1][0] += a1 * v0; acc[1][1] += a1 * v1;
        acc[2][0] += a2 * v0; acc[2][1] += a2 * v1;
        acc[3][0] += a3 * v0; acc[3][1] += a3 * v1;
        acc[4][0] += a4 * v0; acc[4][1] += a4 * v1;
        if ((t & 255) == tid) {
            p[0] += a0 * a1; p[1] += a0 * a2; p[2] += a0 * a3; p[3] += a0 * a4;
            p[4] += a1 * a2; p[5] += a1 * a3; p[6] += a1 * a4;
            p[7] += a2 * a3; p[8] += a2 * a4; p[9] += a3 * a4;
        }
    }
    #pragma unroll
    for (int h = 0; h < HEADS; h++) {
        out[(size_t)b * (HEADS * 2 * H) + h * (2 * H) + tid]     = acc[h][0];
        out[(size_t)b * (HEADS * 2 * H) + h * (2 * H) + H + tid] = acc[h][1];
    }

    __shared__ float red[10][4];
    int lane = tid & 63, wave = tid >> 6;
    #pragma unroll
    for (int i = 0; i < 10; i++) {
        float v = p[i];
        for (int off = 32; off; off >>= 1) v += __shfl_xor(v, off, 64);
        if (lane == 0) red[i][wave] = v;
    }
    __syncthreads();
    if (tid == 0) {
        float s = 0.f;
        #pragma unroll
        for (int i = 0; i < 10; i++) {
            float P = red[i][0] + red[i][1] + red[i][2] + red[i][3];
            s += 2.f * P * P;
        }
        part[b] = s;
    }
}

__global__ __launch_bounds__(128) void final_kernel(const float* __restrict__ part,
                                                    float* __restrict__ out) {
    int tid = threadIdx.x;
    float v = part[tid];
    for (int off = 32; off; off >>= 1) v += __shfl_xor(v, off, 64);
    __shared__ float r2[2];
    if ((tid & 63) == 0) r2[tid >> 6] = v;
    __syncthreads();
    if (tid == 0) out[(size_t)B * HEADS * 2 * H] = (r2[0] + r2[1]) * (1.f / (float)B);
}

// ---------------- host launcher ----------------
extern "C" void kernel_launch(void* const* d_in, const int* in_sizes, int n_in,
                              void* d_out, int out_size, void* d_ws, size_t ws_size,
                              hipStream_t stream) {
    const int*   word_ids = (const int*)d_in[0];
    const int*   lengths  = (const int*)d_in[1];
    const float* emb      = (const float*)d_in[2];
    const float* W_ih_f   = (const float*)d_in[3];
    const float* W_hh_f   = (const float*)d_in[4];
    const float* b_f      = (const float*)d_in[5];
    const float* W_ih_b   = (const float*)d_in[6];
    const float* W_hh_b   = (const float*)d_in[7];
    const float* b_b      = (const float*)d_in[8];
    const float* W_s1     = (const float*)d_in[9];
    const float* W_s2     = (const float*)d_in[10];
    float* out = (float*)d_out;

    char* ws = (char*)d_ws;
    unsigned short* wbt16 = (unsigned short*)(ws + WBT_OFF);
    unsigned*       wbt   = (unsigned*)(ws + WBT_OFF);
    unsigned short* wih16 = (unsigned short*)(ws + WIH_OFF);
    unsigned*       wihu  = (unsigned*)(ws + WIH_OFF);
    unsigned short* ws1m16 = (unsigned short*)(ws + WS1M_OFF);
    const uint4*    ws1m4  = (const uint4*)(ws + WS1M_OFF);
    float* pxc    = (float*)(ws + PX_OFF);
    float* hc     = (float*)(ws + HC_OFF);
    float* hbuf   = (float*)(ws + HBUF_OFF);
    float* cstate = (float*)(ws + CST_OFF);
    float* Abuf   = (float*)(ws + A_OFF);
    float* part   = (float*)(ws + PART_OFF);
    bool have_embh = (ws_size >= EMBH_END);
    unsigned short* embh16 = have_embh ? (unsigned short*)(ws + EMBH_OFF) : nullptr;
    const unsigned* embhu  = have_embh ? (const unsigned*)(ws + EMBH_OFF) : nullptr;

    prep_kernel<<<2080, 256, 0, stream>>>(W_hh_f, W_hh_b, W_ih_f, W_ih_b, W_s1, emb,
                                          wbt16, wih16, ws1m16, embh16);

    for (int c = 0; c < 8; c++) {
        proj_kernel<<<dim3(16, 128, 2), 256, 0, stream>>>(
            word_ids, lengths, emb, embhu, wihu, b_f, b_b, pxc, c);
        lstm6_kernel<<<dim3(128, 2), 1024, LSTM_LDS_BYTES, stream>>>(
            lengths, wbt, pxc, hc, hbuf, cstate, c);
    }

    logits_kernel<<<dim3(8, 128), 256, 0, stream>>>(lengths, hc, ws1m4, W_s2, Abuf);
    softmax_kernel<<<B * HEADS, 256, 0, stream>>>(Abuf);
    attnM_kernel<<<B, 256, 0, stream>>>(lengths, Abuf, hc, out, part);
    final_kernel<<<1, 128, 0, stream>>>(part, out);
}

// Round 5
// 1209.448 us; speedup vs baseline: 2.4757x; 1.0776x over previous
//
#include <hip/hip_runtime.h>
#include <math.h>

#define T 512
#define B 128
#define E 256
#define H 256
#define G 1024   // 4H
#define DA 25
#define HEADS 5
#define V 2080
#define NEGINF (-1e30f)

// ---------------- workspace layout (bytes) ----------------
static constexpr size_t WBT_OFF  = 0;           // [2][128 k2][256 j][4 gate] uint (f16 pair W_hh) 1,048,576
static constexpr size_t WIH_OFF  = 1048576;     // [2][1024 g][256 e] ushort (f16 W_ih)            1,048,576
static constexpr size_t WS1M_OFF = 2097152;     // [32 r][512 k] ushort (f16 W_s1, rows 25..31 = 0)   32,768
static constexpr size_t PX_OFF   = 2148352;     // [2][64][128][1024] f32     67,108,864
static constexpr size_t HC_OFF   = 69257216;    // [128][512][512] f32       134,217,728
static constexpr size_t HBUF_OFF = 203474944;   // [2][128 b][256 j] f32         262,144
static constexpr size_t CST_OFF  = 203737088;   // [2][128][256] f32 c-state     262,144
static constexpr size_t A_OFF    = 203999232;   // [128][5][512] f32           1,310,720
static constexpr size_t PART_OFF = 205309952;   // [128] f32                         512
static constexpr size_t EMBH_OFF = 205310464;   // [2080][256] ushort (f16 emb) 1,064,960
static constexpr size_t EMBH_END = EMBH_OFF + (size_t)V * E * 2;
// attnM partials overlay the (dead-by-then) PX region:
static constexpr size_t PM_OFF   = PX_OFF;                 // [8 tc][128 b][5 h][512] f32 = 10,485,760
static constexpr size_t PP_OFF   = PX_OFF + 10485760;      // [8 tc][128 b][16] f32     =     65,536

// ---- lstm6 dynamic LDS layout (bytes) ----
static constexpr unsigned LSTM_LDS_BYTES = 160304;

typedef _Float16 half2v __attribute__((ext_vector_type(2)));
typedef _Float16 half8_ __attribute__((ext_vector_type(8)));
typedef float    f32x4  __attribute__((ext_vector_type(4)));

#if __has_builtin(__builtin_amdgcn_exp2f)
#define EXP2F_(x) __builtin_amdgcn_exp2f(x)
#else
#define EXP2F_(x) exp2f(x)
#endif
#if __has_builtin(__builtin_amdgcn_rcpf)
#define RCPF_(x) __builtin_amdgcn_rcpf(x)
#else
#define RCPF_(x) (1.0f / (x))
#endif

__device__ __forceinline__ float sigmoidf_(float x) { return 1.f / (1.f + expf(-x)); }

// fast sigmoid/tanh on v_exp/v_rcp; exact +-1 / 0..1 saturation at extremes
__device__ __forceinline__ float sigmoid_fast_(float x) {
    return RCPF_(1.f + EXP2F_(-1.44269504f * x));
}
__device__ __forceinline__ float tanh_fast_(float x) {
    return 1.f - 2.f * RCPF_(1.f + EXP2F_(2.88539008f * x));
}

__device__ __forceinline__ unsigned short f2h_(float f) {   // f32 -> f16 bits
    _Float16 h = (_Float16)f;
    unsigned short u;
    __builtin_memcpy(&u, &h, 2);
    return u;
}

// dot2: acc += w.lo*h.lo + w.hi*h.hi  (f32 accumulate)
__device__ __forceinline__ float fdot2_(unsigned w, half2v h, float acc) {
#if __has_builtin(__builtin_amdgcn_fdot2)
    half2v wv;
    __builtin_memcpy(&wv, &w, 4);
    return __builtin_amdgcn_fdot2(wv, h, acc, false);
#else
    unsigned short lo = (unsigned short)(w & 0xffffu), hi = (unsigned short)(w >> 16);
    _Float16 w0, w1;
    __builtin_memcpy(&w0, &lo, 2);
    __builtin_memcpy(&w1, &hi, 2);
    return fmaf((float)w0, (float)h[0], fmaf((float)w1, (float)h[1], acc));
#endif
}

__device__ __forceinline__ half2v packh2_(float a, float b) {
    half2v h;
    h[0] = (_Float16)a;
    h[1] = (_Float16)b;
    return h;
}

// ---------------- prep: pack W_hh + W_ih + W_s1 (+ emb) to f16 -------------
__global__ __launch_bounds__(256) void prep_kernel(const float* __restrict__ Whf,
                                                   const float* __restrict__ Whb,
                                                   const float* __restrict__ Wif,
                                                   const float* __restrict__ Wib,
                                                   const float* __restrict__ Ws1,
                                                   const float* __restrict__ emb,
                                                   unsigned short* __restrict__ wbt,
                                                   unsigned short* __restrict__ wih,
                                                   unsigned short* __restrict__ ws1m,
                                                   unsigned short* __restrict__ embh) {
    int idx = blockIdx.x * 256 + threadIdx.x;
    if (idx < 2 * G * H) {
        int d = idx >> 18;
        int rem = idx & 262143;
        int r = rem >> 8;                        // gate row 0..1023
        int k = rem & 255;                       // h index
        const float* W = d ? Whb : Whf;
        int gate = r >> 8, j = r & 255;
        int k2 = k >> 1, ke = k & 1;
        wbt[(((size_t)d * 128 + k2) * 256 + j) * 8 + gate * 2 + ke] = f2h_(W[(size_t)r * H + k]);
        const float* Wi = d ? Wib : Wif;
        wih[((size_t)d * G + r) * 256 + k] = f2h_(Wi[(size_t)r * E + k]);
    }
    if (idx < 32 * 512) {                        // W_s1 as [32][512] f16, rows 25..31 zero
        int r = idx >> 9, k = idx & 511;
        ws1m[idx] = (r < DA) ? f2h_(Ws1[r * 512 + k]) : (unsigned short)0;
    }
    if (embh && idx < V * E) embh[idx] = f2h_(emb[idx]);
}

// ---------------- input projection: MFMA f16 (64s x 64g x K=256 per block) ----
__global__ __launch_bounds__(256) void proj_kernel(const int* __restrict__ word_ids,
                                                   const int* __restrict__ lengths,
                                                   const float* __restrict__ emb,
                                                   const unsigned* __restrict__ embh,
                                                   const unsigned* __restrict__ wih,
                                                   const float* __restrict__ bf,
                                                   const float* __restrict__ bb,
                                                   float* __restrict__ pxc, int chunk) {
    int g0 = blockIdx.x * 64;
    int b  = blockIdx.y;
    int d  = blockIdx.z;
    int len = lengths[b];
    int t0 = chunk * 64;
    if (t0 >= len) return;
    const float* bias = d ? bb : bf;

    __shared__ _Float16 A_s[64][264];   // 33792 B, row stride 528 B (16B aligned)
    __shared__ _Float16 B_s[64][264];   // 33792 B

    int tid = threadIdx.x;
    int sr = tid >> 2, sq = tid & 3;    // staging: 4 threads per 512B row, 8 uint4 each

    {
        int t = t0 + sr;
        int src = d ? max(len - 1 - t, 0) : t;
        int wid = word_ids[b * T + src];
        if (embh) {
            const uint4* ap = (const uint4*)embh + (size_t)wid * 32;
            #pragma unroll
            for (int c = 0; c < 8; c++) {
                uint4 v = ap[sq * 8 + c];
                *(uint4*)&A_s[sr][(sq * 8 + c) * 8] = v;
            }
        } else {
            const float4* ep = (const float4*)(emb + (size_t)wid * E);
            #pragma unroll
            for (int c = 0; c < 8; c++) {
                float4 x0 = ep[(sq * 8 + c) * 2];
                float4 x1 = ep[(sq * 8 + c) * 2 + 1];
                half8_ hv;
                hv[0] = (_Float16)x0.x; hv[1] = (_Float16)x0.y;
                hv[2] = (_Float16)x0.z; hv[3] = (_Float16)x0.w;
                hv[4] = (_Float16)x1.x; hv[5] = (_Float16)x1.y;
                hv[6] = (_Float16)x1.z; hv[7] = (_Float16)x1.w;
                *(half8_*)&A_s[sr][(sq * 8 + c) * 8] = hv;
            }
        }
        const uint4* bp = (const uint4*)wih + ((size_t)d * G + g0 + sr) * 32;
        #pragma unroll
        for (int c = 0; c < 8; c++) {
            uint4 v = bp[sq * 8 + c];
            *(uint4*)&B_s[sr][(sq * 8 + c) * 8] = v;
        }
    }
    __syncthreads();

    int lane = tid & 63, wave = tid >> 6;
    int m0 = (wave >> 1) * 32;          // s quadrant base
    int n0 = (wave & 1) * 32;           // g quadrant base
    int lr = lane & 15, lq = lane >> 4;

    f32x4 acc00 = {0.f, 0.f, 0.f, 0.f}, acc01 = {0.f, 0.f, 0.f, 0.f};
    f32x4 acc10 = {0.f, 0.f, 0.f, 0.f}, acc11 = {0.f, 0.f, 0.f, 0.f};

    #pragma unroll
    for (int k0 = 0; k0 < E; k0 += 32) {
        int ka = k0 + lq * 8;
        half8_ af0 = *(const half8_*)&A_s[m0 + lr][ka];
        half8_ af1 = *(const half8_*)&A_s[m0 + 16 + lr][ka];
        half8_ bf0 = *(const half8_*)&B_s[n0 + lr][ka];
        half8_ bf1 = *(const half8_*)&B_s[n0 + 16 + lr][ka];
        acc00 = __builtin_amdgcn_mfma_f32_16x16x32_f16(af0, bf0, acc00, 0, 0, 0);
        acc01 = __builtin_amdgcn_mfma_f32_16x16x32_f16(af0, bf1, acc01, 0, 0, 0);
        acc10 = __builtin_amdgcn_mfma_f32_16x16x32_f16(af1, bf0, acc10, 0, 0, 0);
        acc11 = __builtin_amdgcn_mfma_f32_16x16x32_f16(af1, bf1, acc11, 0, 0, 0);
    }

    // C/D layout (m89-verified): col = lane&15, row = (lane>>4)*4 + reg
    float bia0 = bias[g0 + n0 + lr];
    float bia1 = bias[g0 + n0 + 16 + lr];
    #pragma unroll
    for (int mi = 0; mi < 2; mi++) {
        f32x4 ar0 = mi ? acc10 : acc00;
        f32x4 ar1 = mi ? acc11 : acc01;
        #pragma unroll
        for (int rr = 0; rr < 4; rr++) {
            int s = m0 + mi * 16 + lq * 4 + rr;
            float* dst = pxc + ((size_t)(d * 64 + s) * B + b) * G + g0;
            dst[n0 + lr]      = ar0[rr] + bia0;
            dst[n0 + 16 + lr] = ar1[rr] + bia1;
        }
    }
}

// ---------------- LSTM recurrence: residency-split W, tuned schedule ------
__global__ __launch_bounds__(1024, 4) void lstm6_kernel(const int* __restrict__ lengths,
                                                        const unsigned* __restrict__ wbt,
                                                        const float* __restrict__ pxc,
                                                        float* __restrict__ hc_out,
                                                        float* __restrict__ hbuf,
                                                        float* __restrict__ cstate,
                                                        int chunk) {
    int b   = blockIdx.x;
    int d   = blockIdx.y;
    int tid = threadIdx.x;
    int j  = tid & 255;
    int kq = tid >> 8;                 // 0..3 (wave-uniform)

    int len = lengths[b];
    int t0 = chunk * 64;
    if (t0 >= len) return;
    int tend = min(t0 + 64, len);

    extern __shared__ char smem[];
    unsigned* hh   = (unsigned*)smem;                // [128]
    float4*   part = (float4*)(smem + 512);          // [3][257]
    uint4*    wst  = (uint4*)(smem + 12848);         // [36][256]
    unsigned short* hh16 = (unsigned short*)smem;    // alias: h as f16[256]

    float* hbufg = hbuf + ((size_t)d * B + b) * 256;

    float c = 0.f, hreg = 0.f;
    if (chunk == 0) {
        if (tid < 128) hh[tid] = 0u;
    } else {
        if (kq == 0) c = cstate[((size_t)d * B + b) * H + j];
        if (tid < 128) {
            half2v hv2 = packh2_(hbufg[2 * tid], hbufg[2 * tid + 1]);
            unsigned hu;
            __builtin_memcpy(&hu, &hv2, 4);
            hh[tid] = hu;
        }
    }

    // thread's W rows: k2 in [kq*32, kq*32+32), column j
    const uint4* wp  = (const uint4*)wbt + ((size_t)d * 128 + kq * 32) * 256 + j;
    const float* pxd = pxc + (size_t)d * 64 * B * G;

    // stage k2 0..8 into LDS (thread-private; written+read by same thread)
    #pragma unroll
    for (int r = 0; r < 9; r++)
        wst[(kq * 9 + r) * 256 + j] = wp[(size_t)r * 256];
    // resident k2 9..23 in named registers (15 x uint4 = 60 VGPR raw)
    uint4 wr0  = wp[9 * 256],  wr1  = wp[10 * 256], wr2  = wp[11 * 256];
    uint4 wr3  = wp[12 * 256], wr4  = wp[13 * 256], wr5  = wp[14 * 256];
    uint4 wr6  = wp[15 * 256], wr7  = wp[16 * 256], wr8  = wp[17 * 256];
    uint4 wr9  = wp[18 * 256], wr10 = wp[19 * 256], wr11 = wp[20 * 256];
    uint4 wr12 = wp[21 * 256], wr13 = wp[22 * 256], wr14 = wp[23 * 256];
    __syncthreads();

    int hlane = kq * 32 + (tid & 31);   // lanes 32..63 duplicate 0..31 (broadcast pair, free)
    int pendpos = -1;

    for (int t = t0; t < tend; t++) {
        int s = t - t0;

        // deferred hc_out store for step t-1: drains during this dot phase
        if (kq == 0 && pendpos >= 0)
            hc_out[((size_t)b * T + pendpos) * (2 * H) + d * H + j] = hreg;

        float p0, p1, p2, p3;
        if (kq == 0) {
            const float* pxs = pxd + ((size_t)s * B + b) * G;
            p0 = pxs[j];
            p1 = pxs[256 + j];
            p2 = pxs[512 + j];
            p3 = pxs[768 + j];
        }

        unsigned hlv = hh[hlane];       // one LDS b32/lane; rows via readlane
        // issue streamed group 0 (rows 24..27) early
        uint4 wv0 = wp[24 * 256], wv1 = wp[25 * 256], wv2 = wp[26 * 256], wv3 = wp[27 * 256];

        float a0 = 0.f, a1 = 0.f, a2 = 0.f, a3 = 0.f;

        #define HROW(IDX) __builtin_amdgcn_readlane(hlv, IDX)
        #define DOT4(WV, IDX)                                          \
            { unsigned hu = HROW(IDX); half2v hx;                      \
              __builtin_memcpy(&hx, &hu, 4);                           \
              a0 = fdot2_(WV.x, hx, a0); a1 = fdot2_(WV.y, hx, a1);    \
              a2 = fdot2_(WV.z, hx, a2); a3 = fdot2_(WV.w, hx, a3); }

        // LDS-cached k2 0..8 (covers group-0 L2 latency)
        #pragma unroll
        for (int r = 0; r < 9; r++) {
            uint4 wv = wst[(kq * 9 + r) * 256 + j];
            DOT4(wv, r)
        }
        // consume streamed group 0
        DOT4(wv0, 24) DOT4(wv1, 25) DOT4(wv2, 26) DOT4(wv3, 27)
        // issue streamed group 1 (rows 28..31)
        uint4 wv4 = wp[28 * 256], wv5 = wp[29 * 256], wv6 = wp[30 * 256], wv7 = wp[31 * 256];
        // register-resident k2 9..23 (covers group-1 L2 latency)
        DOT4(wr0, 9)  DOT4(wr1, 10)  DOT4(wr2, 11)  DOT4(wr3, 12)
        DOT4(wr4, 13) DOT4(wr5, 14)  DOT4(wr6, 15)  DOT4(wr7, 16)
        DOT4(wr8, 17) DOT4(wr9, 18)  DOT4(wr10, 19) DOT4(wr11, 20)
        DOT4(wr12, 21) DOT4(wr13, 22) DOT4(wr14, 23)
        // consume streamed group 1
        DOT4(wv4, 28) DOT4(wv5, 29) DOT4(wv6, 30) DOT4(wv7, 31)
        #undef DOT4
        #undef HROW

        if (kq > 0) part[(kq - 1) * 257 + j] = make_float4(a0, a1, a2, a3);
        __syncthreads();           // barrier 1: partials ready; hh reads done

        if (kq == 0) {
            __builtin_amdgcn_s_setprio(1);
            #pragma unroll
            for (int q = 0; q < 3; q++) {
                float4 qv = part[q * 257 + j];
                a0 += qv.x; a1 += qv.y; a2 += qv.z; a3 += qv.w;
            }
            a0 += p0; a1 += p1; a2 += p2; a3 += p3;

            float ig = sigmoid_fast_(a0), fg = sigmoid_fast_(a1), og = sigmoid_fast_(a3);
            c = fg * c + ig * tanh_fast_(a2);
            float h = og * tanh_fast_(c);
            hreg = h;
            hh16[j] = f2h_(h);      // per-thread b16 write (no shfl)
            pendpos = d ? (len - 1 - t) : t;
            __builtin_amdgcn_s_setprio(0);
        }
        __syncthreads();           // barrier 2: hh updated before next reads
    }

    if (kq == 0) {
        if (pendpos >= 0)
            hc_out[((size_t)b * T + pendpos) * (2 * H) + d * H + j] = hreg;
        cstate[((size_t)d * B + b) * H + j] = c;
        hbufg[j] = hreg;
    }
}

// ---------------- attention logits via MFMA --------------------------------
__global__ __launch_bounds__(256) void logits_kernel(const int* __restrict__ lengths,
                                                     const float* __restrict__ hc,
                                                     const uint4* __restrict__ ws1m,
                                                     const float* __restrict__ Ws2,
                                                     float* __restrict__ S) {
    __shared__ _Float16 A_s[64][520];   // 66560 B (pad: pitch 1040 B ~ bank+4)
    __shared__ _Float16 B_s[32][520];   // 33280 B

    int b = blockIdx.y, tt = blockIdx.x;
    int tid = threadIdx.x;
    int len = lengths[b];
    int t0 = tt * 64;

    int lane = tid & 63, wave = tid >> 6;
    int lr = lane & 15, lq = lane >> 4;
    int m0 = wave * 16;

    if (t0 >= len) {
        if (lr < HEADS) {
            #pragma unroll
            for (int rr = 0; rr < 4; rr++) {
                int t = t0 + m0 + lq * 4 + rr;
                S[((size_t)b * HEADS + lr) * T + t] = NEGINF;
            }
        }
        return;
    }

    // stage B: 32 rows x 512 f16 = 2048 uint4; 8 per thread
    {
        #pragma unroll
        for (int i = 0; i < 8; i++) {
            int u = tid + i * 256;
            int r = u >> 6, c8 = u & 63;
            *(uint4*)&B_s[r][c8 * 8] = ws1m[u];
        }
    }
    // stage A: 64 hc rows -> f16; thread = (row = tid>>2, quarter = tid&3)
    {
        int row = tid >> 2, q = tid & 3;
        int t = t0 + row;
        const float4* ep = (const float4*)(hc + ((size_t)b * T + t) * 512 + q * 128);
        #pragma unroll
        for (int c = 0; c < 16; c++) {
            float4 x0 = ep[2 * c];
            float4 x1 = ep[2 * c + 1];
            half8_ hv;
            hv[0] = (_Float16)x0.x; hv[1] = (_Float16)x0.y;
            hv[2] = (_Float16)x0.z; hv[3] = (_Float16)x0.w;
            hv[4] = (_Float16)x1.x; hv[5] = (_Float16)x1.y;
            hv[6] = (_Float16)x1.z; hv[7] = (_Float16)x1.w;
            *(half8_*)&A_s[row][q * 128 + c * 8] = hv;
        }
    }
    __syncthreads();

    f32x4 acc0 = {0.f, 0.f, 0.f, 0.f};   // n-tile 0: r = lr
    f32x4 acc1 = {0.f, 0.f, 0.f, 0.f};   // n-tile 1: r = lr + 16
    #pragma unroll
    for (int ks = 0; ks < 16; ks++) {
        int ka = ks * 32 + lq * 8;
        half8_ af  = *(const half8_*)&A_s[m0 + lr][ka];
        half8_ bf0 = *(const half8_*)&B_s[lr][ka];
        half8_ bf1 = *(const half8_*)&B_s[16 + lr][ka];
        acc0 = __builtin_amdgcn_mfma_f32_16x16x32_f16(af, bf0, acc0, 0, 0, 0);
        acc1 = __builtin_amdgcn_mfma_f32_16x16x32_f16(af, bf1, acc1, 0, 0, 0);
    }

    // W_s2 weights for this lane's two r-slots (r=lr, r=lr+16)
    float w2a[HEADS], w2b[HEADS];
    #pragma unroll
    for (int h = 0; h < HEADS; h++) {
        w2a[h] = Ws2[h * DA + lr];
        w2b[h] = (lr + 16 < DA) ? Ws2[h * DA + 16 + lr] : 0.f;
    }

    #pragma unroll
    for (int rr = 0; rr < 4; rr++) {
        float y0 = tanhf(acc0[rr]);
        float y1 = tanhf(acc1[rr]);
        int t = t0 + m0 + lq * 4 + rr;
        float sv[HEADS];
        #pragma unroll
        for (int h = 0; h < HEADS; h++) {
            float v = y0 * w2a[h] + y1 * w2b[h];
            v += __shfl_xor(v, 1, 16);
            v += __shfl_xor(v, 2, 16);
            v += __shfl_xor(v, 4, 16);
            v += __shfl_xor(v, 8, 16);
            sv[h] = v;
        }
        if (lr < HEADS) {
            S[((size_t)b * HEADS + lr) * T + t] = (t < len) ? sv[lr] : NEGINF;
        }
    }
}

// ---------------- masked softmax over T, in place ----------------
__global__ __launch_bounds__(256) void softmax_kernel(float* __restrict__ S) {
    int row = blockIdx.x;
    float* p = S + (size_t)row * T;
    int tid = threadIdx.x;
    int lane = tid & 63, wave = tid >> 6;
    __shared__ float rr[4], ss[4];

    float mx = NEGINF;
    #pragma unroll
    for (int i = 0; i < 2; i++) mx = fmaxf(mx, p[tid + i * 256]);
    for (int off = 32; off; off >>= 1) mx = fmaxf(mx, __shfl_xor(mx, off, 64));
    if (lane == 0) rr[wave] = mx;
    __syncthreads();
    mx = fmaxf(fmaxf(rr[0], rr[1]), fmaxf(rr[2], rr[3]));

    float e[2], sum = 0.f;
    #pragma unroll
    for (int i = 0; i < 2; i++) { e[i] = expf(p[tid + i * 256] - mx); sum += e[i]; }
    for (int off = 32; off; off >>= 1) sum += __shfl_xor(sum, off, 64);
    if (lane == 0) ss[wave] = sum;
    __syncthreads();
    sum = ss[0] + ss[1] + ss[2] + ss[3];
    float inv = 1.f / sum;
    #pragma unroll
    for (int i = 0; i < 2; i++) p[tid + i * 256] = e[i] * inv;
}

// ---------------- attnM partials: 8 t-chunks x 128 b ----------------------
// Splits the serial t-loop 8x for TLP (old single-block version was
// latency-bound: VALUBusy 1.5%, occupancy 2.7%). Partial M -> pm, partial
// penal dot-sums -> pp; reduced by attnM_reduce_kernel.
__global__ __launch_bounds__(256) void attnM_part_kernel(const int* __restrict__ lengths,
                                                         const float* __restrict__ A,
                                                         const float* __restrict__ hc,
                                                         float* __restrict__ pm,
                                                         float* __restrict__ pp) {
    int tc = blockIdx.x, b = blockIdx.y, tid = threadIdx.x;
    int len = lengths[b];
    int t0 = tc * 64;
    int tend = min(t0 + 64, len);
    const float* Ab  = A + (size_t)b * HEADS * T;
    const float* hcb = hc + (size_t)b * T * (2 * H);
    float acc[HEADS][2];
    #pragma unroll
    for (int h = 0; h < HEADS; h++) { acc[h][0] = 0.f; acc[h][1] = 0.f; }
    float p[10];
    #pragma unroll
    for (int i = 0; i < 10; i++) p[i] = 0.f;

    for (int t = t0; t < tend; t++) {
        float v0 = hcb[(size_t)t * (2 * H) + tid];
        float v1 = hcb[(size_t)t * (2 * H) + H + tid];
        float a0 = Ab[t], a1 = Ab[T + t], a2 = Ab[2 * T + t], a3 = Ab[3 * T + t], a4 = Ab[4 * T + t];
        acc[0][0] += a0 * v0; acc[0][1] += a0 * v1;
        acc[1][0] += a1 * v0; acc[1][1] += a1 * v1;
        acc[2][0] += a2 * v0; acc[2][1] += a2 * v1;
        acc[3][0] += a3 * v0; acc[3][1] += a3 * v1;
        acc[4][0] += a4 * v0; acc[4][1] += a4 * v1;
        if ((t & 255) == tid) {
            p[0] += a0 * a1; p[1] += a0 * a2; p[2] += a0 * a3; p[3] += a0 * a4;
            p[4] += a1 * a2; p[5] += a1 * a3; p[6] += a1 * a4;
            p[7] += a2 * a3; p[8] += a2 * a4; p[9] += a3 * a4;
        }
    }
    size_t base = ((size_t)tc * B + b) * (HEADS * 2 * H);
    #pragma unroll
    for (int h = 0; h < HEADS; h++) {
        pm[base + h * (2 * H) + tid]     = acc[h][0];
        pm[base + h * (2 * H) + H + tid] = acc[h][1];
    }

    __shared__ float red[10][4];
    int lane = tid & 63, wave = tid >> 6;
    #pragma unroll
    for (int i = 0; i < 10; i++) {
        float v = p[i];
        for (int off = 32; off; off >>= 1) v += __shfl_xor(v, off, 64);
        if (lane == 0) red[i][wave] = v;
    }
    __syncthreads();
    if (tid < 10)
        pp[((size_t)tc * B + b) * 16 + tid] =
            red[tid][0] + red[tid][1] + red[tid][2] + red[tid][3];
}

// ---------------- reduce partials -> out + penal per b ---------------------
__global__ __launch_bounds__(256) void attnM_reduce_kernel(const float* __restrict__ pm,
                                                           const float* __restrict__ pp,
                                                           float* __restrict__ out,
                                                           float* __restrict__ part) {
    int b = blockIdx.x, tid = threadIdx.x;
    #pragma unroll
    for (int h = 0; h < HEADS; h++) {
        float a0 = 0.f, a1 = 0.f;
        #pragma unroll
        for (int tc = 0; tc < 8; tc++) {
            size_t base = ((size_t)tc * B + b) * (HEADS * 2 * H) + h * (2 * H);
            a0 += pm[base + tid];
            a1 += pm[base + H + tid];
        }
        out[(size_t)b * (HEADS * 2 * H) + h * (2 * H) + tid]     = a0;
        out[(size_t)b * (HEADS * 2 * H) + h * (2 * H) + H + tid] = a1;
    }
    __shared__ float sred[10];
    if (tid < 10) {
        float P = 0.f;
        #pragma unroll
        for (int tc = 0; tc < 8; tc++) P += pp[((size_t)tc * B + b) * 16 + tid];
        sred[tid] = 2.f * P * P;
    }
    __syncthreads();
    if (tid == 0) {
        float s = 0.f;
        #pragma unroll
        for (int i = 0; i < 10; i++) s += sred[i];
        part[b] = s;
    }
}

__global__ __launch_bounds__(128) void final_kernel(const float* __restrict__ part,
                                                    float* __restrict__ out) {
    int tid = threadIdx.x;
    float v = part[tid];
    for (int off = 32; off; off >>= 1) v += __shfl_xor(v, off, 64);
    __shared__ float r2[2];
    if ((tid & 63) == 0) r2[tid >> 6] = v;
    __syncthreads();
    if (tid == 0) out[(size_t)B * HEADS * 2 * H] = (r2[0] + r2[1]) * (1.f / (float)B);
}

// ---------------- host launcher ----------------
extern "C" void kernel_launch(void* const* d_in, const int* in_sizes, int n_in,
                              void* d_out, int out_size, void* d_ws, size_t ws_size,
                              hipStream_t stream) {
    const int*   word_ids = (const int*)d_in[0];
    const int*   lengths  = (const int*)d_in[1];
    const float* emb      = (const float*)d_in[2];
    const float* W_ih_f   = (const float*)d_in[3];
    const float* W_hh_f   = (const float*)d_in[4];
    const float* b_f      = (const float*)d_in[5];
    const float* W_ih_b   = (const float*)d_in[6];
    const float* W_hh_b   = (const float*)d_in[7];
    const float* b_b      = (const float*)d_in[8];
    const float* W_s1     = (const float*)d_in[9];
    const float* W_s2     = (const float*)d_in[10];
    float* out = (float*)d_out;

    char* ws = (char*)d_ws;
    unsigned short* wbt16 = (unsigned short*)(ws + WBT_OFF);
    unsigned*       wbt   = (unsigned*)(ws + WBT_OFF);
    unsigned short* wih16 = (unsigned short*)(ws + WIH_OFF);
    unsigned*       wihu  = (unsigned*)(ws + WIH_OFF);
    unsigned short* ws1m16 = (unsigned short*)(ws + WS1M_OFF);
    const uint4*    ws1m4  = (const uint4*)(ws + WS1M_OFF);
    float* pxc    = (float*)(ws + PX_OFF);
    float* hc     = (float*)(ws + HC_OFF);
    float* hbuf   = (float*)(ws + HBUF_OFF);
    float* cstate = (float*)(ws + CST_OFF);
    float* Abuf   = (float*)(ws + A_OFF);
    float* part   = (float*)(ws + PART_OFF);
    float* pm     = (float*)(ws + PM_OFF);   // overlays dead pxc
    float* pp     = (float*)(ws + PP_OFF);
    bool have_embh = (ws_size >= EMBH_END);
    unsigned short* embh16 = have_embh ? (unsigned short*)(ws + EMBH_OFF) : nullptr;
    const unsigned* embhu  = have_embh ? (const unsigned*)(ws + EMBH_OFF) : nullptr;

    prep_kernel<<<2080, 256, 0, stream>>>(W_hh_f, W_hh_b, W_ih_f, W_ih_b, W_s1, emb,
                                          wbt16, wih16, ws1m16, embh16);

    for (int c = 0; c < 8; c++) {
        proj_kernel<<<dim3(16, 128, 2), 256, 0, stream>>>(
            word_ids, lengths, emb, embhu, wihu, b_f, b_b, pxc, c);
        lstm6_kernel<<<dim3(128, 2), 1024, LSTM_LDS_BYTES, stream>>>(
            lengths, wbt, pxc, hc, hbuf, cstate, c);
    }

    logits_kernel<<<dim3(8, 128), 256, 0, stream>>>(lengths, hc, ws1m4, W_s2, Abuf);
    softmax_kernel<<<B * HEADS, 256, 0, stream>>>(Abuf);
    attnM_part_kernel<<<dim3(8, 128), 256, 0, stream>>>(lengths, Abuf, hc, pm, pp);
    attnM_reduce_kernel<<<B, 256, 0, stream>>>(pm, pp, out, part);
    final_kernel<<<1, 128, 0, stream>>>(part, out);
}

// Round 6
// 1208.376 us; speedup vs baseline: 2.4779x; 1.0009x over previous
//
#include <hip/hip_runtime.h>
#include <math.h>

#define T 512
#define B 128
#define E 256
#define H 256
#define G 1024   // 4H
#define DA 25
#define HEADS 5
#define V 2080
#define NEGINF (-1e30f)

// ---------------- workspace layout (bytes) ----------------
static constexpr size_t WBT_OFF  = 0;           // [2][128 k2][256 j][4 gate] uint (f16 pair W_hh) 1,048,576
static constexpr size_t WIH_OFF  = 1048576;     // [2][1024 g][256 e] ushort (f16 W_ih)            1,048,576
static constexpr size_t WS1M_OFF = 2097152;     // [32 r][512 k] ushort (f16 W_s1, rows 25..31 = 0)   32,768
static constexpr size_t PX_OFF   = 2148352;     // [2][64][128][1024] f32     67,108,864
static constexpr size_t HC_OFF   = 69257216;    // [128][512][512] f32       134,217,728
static constexpr size_t HBUF_OFF = 203474944;   // [2][128 b][256 j] f32         262,144
static constexpr size_t CST_OFF  = 203737088;   // [2][128][256] f32 c-state     262,144
static constexpr size_t A_OFF    = 203999232;   // [128][5][512] f32           1,310,720
static constexpr size_t PART_OFF = 205309952;   // [128] f32                         512
static constexpr size_t EMBH_OFF = 205310464;   // [2080][256] ushort (f16 emb) 1,064,960
static constexpr size_t EMBH_END = EMBH_OFF + (size_t)V * E * 2;
// attnM partials overlay the (dead-by-then) PX region:
static constexpr size_t PM_OFF   = PX_OFF;                 // [8 tc][128 b][5 h][512] f32 = 10,485,760
static constexpr size_t PP_OFF   = PX_OFF + 10485760;      // [8 tc][128 b][16] f32     =     65,536

// ---- lstm6 dynamic LDS layout (bytes) ----
static constexpr unsigned LSTM_LDS_BYTES = 160304;

typedef _Float16 half2v __attribute__((ext_vector_type(2)));
typedef _Float16 half8_ __attribute__((ext_vector_type(8)));
typedef float    f32x4  __attribute__((ext_vector_type(4)));

#if __has_builtin(__builtin_amdgcn_exp2f)
#define EXP2F_(x) __builtin_amdgcn_exp2f(x)
#else
#define EXP2F_(x) exp2f(x)
#endif
#if __has_builtin(__builtin_amdgcn_rcpf)
#define RCPF_(x) __builtin_amdgcn_rcpf(x)
#else
#define RCPF_(x) (1.0f / (x))
#endif

__device__ __forceinline__ float sigmoidf_(float x) { return 1.f / (1.f + expf(-x)); }

// fast sigmoid/tanh on v_exp/v_rcp; exact +-1 / 0..1 saturation at extremes
__device__ __forceinline__ float sigmoid_fast_(float x) {
    return RCPF_(1.f + EXP2F_(-1.44269504f * x));
}
__device__ __forceinline__ float tanh_fast_(float x) {
    return 1.f - 2.f * RCPF_(1.f + EXP2F_(2.88539008f * x));
}

__device__ __forceinline__ unsigned short f2h_(float f) {   // f32 -> f16 bits
    _Float16 h = (_Float16)f;
    unsigned short u;
    __builtin_memcpy(&u, &h, 2);
    return u;
}

// dot2: acc += w.lo*h.lo + w.hi*h.hi  (f32 accumulate)
__device__ __forceinline__ float fdot2_(unsigned w, half2v h, float acc) {
#if __has_builtin(__builtin_amdgcn_fdot2)
    half2v wv;
    __builtin_memcpy(&wv, &w, 4);
    return __builtin_amdgcn_fdot2(wv, h, acc, false);
#else
    unsigned short lo = (unsigned short)(w & 0xffffu), hi = (unsigned short)(w >> 16);
    _Float16 w0, w1;
    __builtin_memcpy(&w0, &lo, 2);
    __builtin_memcpy(&w1, &hi, 2);
    return fmaf((float)w0, (float)h[0], fmaf((float)w1, (float)h[1], acc));
#endif
}

__device__ __forceinline__ half2v packh2_(float a, float b) {
    half2v h;
    h[0] = (_Float16)a;
    h[1] = (_Float16)b;
    return h;
}

// ---------------- prep: pack W_hh + W_ih + W_s1 (+ emb) to f16 -------------
__global__ __launch_bounds__(256) void prep_kernel(const float* __restrict__ Whf,
                                                   const float* __restrict__ Whb,
                                                   const float* __restrict__ Wif,
                                                   const float* __restrict__ Wib,
                                                   const float* __restrict__ Ws1,
                                                   const float* __restrict__ emb,
                                                   unsigned short* __restrict__ wbt,
                                                   unsigned short* __restrict__ wih,
                                                   unsigned short* __restrict__ ws1m,
                                                   unsigned short* __restrict__ embh) {
    int idx = blockIdx.x * 256 + threadIdx.x;
    if (idx < 2 * G * H) {
        int d = idx >> 18;
        int rem = idx & 262143;
        int r = rem >> 8;                        // gate row 0..1023
        int k = rem & 255;                       // h index
        const float* W = d ? Whb : Whf;
        int gate = r >> 8, j = r & 255;
        int k2 = k >> 1, ke = k & 1;
        wbt[(((size_t)d * 128 + k2) * 256 + j) * 8 + gate * 2 + ke] = f2h_(W[(size_t)r * H + k]);
        const float* Wi = d ? Wib : Wif;
        wih[((size_t)d * G + r) * 256 + k] = f2h_(Wi[(size_t)r * E + k]);
    }
    if (idx < 32 * 512) {                        // W_s1 as [32][512] f16, rows 25..31 zero
        int r = idx >> 9, k = idx & 511;
        ws1m[idx] = (r < DA) ? f2h_(Ws1[r * 512 + k]) : (unsigned short)0;
    }
    if (embh && idx < V * E) embh[idx] = f2h_(emb[idx]);
}

// ---------------- input projection: MFMA f16 (64s x 64g x K=256 per block) ----
__global__ __launch_bounds__(256) void proj_kernel(const int* __restrict__ word_ids,
                                                   const int* __restrict__ lengths,
                                                   const float* __restrict__ emb,
                                                   const unsigned* __restrict__ embh,
                                                   const unsigned* __restrict__ wih,
                                                   const float* __restrict__ bf,
                                                   const float* __restrict__ bb,
                                                   float* __restrict__ pxc, int chunk) {
    int g0 = blockIdx.x * 64;
    int b  = blockIdx.y;
    int d  = blockIdx.z;
    int len = lengths[b];
    int t0 = chunk * 64;
    if (t0 >= len) return;
    const float* bias = d ? bb : bf;

    __shared__ _Float16 A_s[64][264];   // 33792 B, row stride 528 B (16B aligned)
    __shared__ _Float16 B_s[64][264];   // 33792 B

    int tid = threadIdx.x;
    int sr = tid >> 2, sq = tid & 3;    // staging: 4 threads per 512B row, 8 uint4 each

    {
        int t = t0 + sr;
        int src = d ? max(len - 1 - t, 0) : t;
        int wid = word_ids[b * T + src];
        if (embh) {
            const uint4* ap = (const uint4*)embh + (size_t)wid * 32;
            #pragma unroll
            for (int c = 0; c < 8; c++) {
                uint4 v = ap[sq * 8 + c];
                *(uint4*)&A_s[sr][(sq * 8 + c) * 8] = v;
            }
        } else {
            const float4* ep = (const float4*)(emb + (size_t)wid * E);
            #pragma unroll
            for (int c = 0; c < 8; c++) {
                float4 x0 = ep[(sq * 8 + c) * 2];
                float4 x1 = ep[(sq * 8 + c) * 2 + 1];
                half8_ hv;
                hv[0] = (_Float16)x0.x; hv[1] = (_Float16)x0.y;
                hv[2] = (_Float16)x0.z; hv[3] = (_Float16)x0.w;
                hv[4] = (_Float16)x1.x; hv[5] = (_Float16)x1.y;
                hv[6] = (_Float16)x1.z; hv[7] = (_Float16)x1.w;
                *(half8_*)&A_s[sr][(sq * 8 + c) * 8] = hv;
            }
        }
        const uint4* bp = (const uint4*)wih + ((size_t)d * G + g0 + sr) * 32;
        #pragma unroll
        for (int c = 0; c < 8; c++) {
            uint4 v = bp[sq * 8 + c];
            *(uint4*)&B_s[sr][(sq * 8 + c) * 8] = v;
        }
    }
    __syncthreads();

    int lane = tid & 63, wave = tid >> 6;
    int m0 = (wave >> 1) * 32;          // s quadrant base
    int n0 = (wave & 1) * 32;           // g quadrant base
    int lr = lane & 15, lq = lane >> 4;

    f32x4 acc00 = {0.f, 0.f, 0.f, 0.f}, acc01 = {0.f, 0.f, 0.f, 0.f};
    f32x4 acc10 = {0.f, 0.f, 0.f, 0.f}, acc11 = {0.f, 0.f, 0.f, 0.f};

    #pragma unroll
    for (int k0 = 0; k0 < E; k0 += 32) {
        int ka = k0 + lq * 8;
        half8_ af0 = *(const half8_*)&A_s[m0 + lr][ka];
        half8_ af1 = *(const half8_*)&A_s[m0 + 16 + lr][ka];
        half8_ bf0 = *(const half8_*)&B_s[n0 + lr][ka];
        half8_ bf1 = *(const half8_*)&B_s[n0 + 16 + lr][ka];
        acc00 = __builtin_amdgcn_mfma_f32_16x16x32_f16(af0, bf0, acc00, 0, 0, 0);
        acc01 = __builtin_amdgcn_mfma_f32_16x16x32_f16(af0, bf1, acc01, 0, 0, 0);
        acc10 = __builtin_amdgcn_mfma_f32_16x16x32_f16(af1, bf0, acc10, 0, 0, 0);
        acc11 = __builtin_amdgcn_mfma_f32_16x16x32_f16(af1, bf1, acc11, 0, 0, 0);
    }

    // C/D layout (m89-verified): col = lane&15, row = (lane>>4)*4 + reg
    float bia0 = bias[g0 + n0 + lr];
    float bia1 = bias[g0 + n0 + 16 + lr];
    #pragma unroll
    for (int mi = 0; mi < 2; mi++) {
        f32x4 ar0 = mi ? acc10 : acc00;
        f32x4 ar1 = mi ? acc11 : acc01;
        #pragma unroll
        for (int rr = 0; rr < 4; rr++) {
            int s = m0 + mi * 16 + lq * 4 + rr;
            float* dst = pxc + ((size_t)(d * 64 + s) * B + b) * G + g0;
            dst[n0 + lr]      = ar0[rr] + bia0;
            dst[n0 + 16 + lr] = ar1[rr] + bia1;
        }
    }
}

// ---------------- LSTM recurrence: FULL residency (23 reg + 9 LDS) --------
// grid (128 b, 2 dir); block 1024 = 16 waves; LDS 160 KB -> 1 block/CU;
// __launch_bounds__(1024,4) -> 128 VGPR budget. W split: 9 rows LDS + 23 rows
// registers (92 VGPR raw; overflow banks in AGPRs, accvgpr_read ~2cyc/use).
// This removes the previous 8-row L2 stream: 128 KB/block/step = ~2285 cyc of
// per-CU L2 time (17.5 TB/s aggregate, 50% of L2 peak) that co-limited the
// step with VALU issue. Zero per-step global weight traffic now.
__global__ __launch_bounds__(1024, 4) void lstm6_kernel(const int* __restrict__ lengths,
                                                        const unsigned* __restrict__ wbt,
                                                        const float* __restrict__ pxc,
                                                        float* __restrict__ hc_out,
                                                        float* __restrict__ hbuf,
                                                        float* __restrict__ cstate,
                                                        int chunk) {
    int b   = blockIdx.x;
    int d   = blockIdx.y;
    int tid = threadIdx.x;
    int j  = tid & 255;
    int kq = tid >> 8;                 // 0..3 (wave-uniform)

    int len = lengths[b];
    int t0 = chunk * 64;
    if (t0 >= len) return;
    int tend = min(t0 + 64, len);

    extern __shared__ char smem[];
    unsigned* hh   = (unsigned*)smem;                // [128]
    float4*   part = (float4*)(smem + 512);          // [3][257]
    uint4*    wst  = (uint4*)(smem + 12848);         // [36][256]
    unsigned short* hh16 = (unsigned short*)smem;    // alias: h as f16[256]

    float* hbufg = hbuf + ((size_t)d * B + b) * 256;

    float c = 0.f, hreg = 0.f;
    if (chunk == 0) {
        if (tid < 128) hh[tid] = 0u;
    } else {
        if (kq == 0) c = cstate[((size_t)d * B + b) * H + j];
        if (tid < 128) {
            half2v hv2 = packh2_(hbufg[2 * tid], hbufg[2 * tid + 1]);
            unsigned hu;
            __builtin_memcpy(&hu, &hv2, 4);
            hh[tid] = hu;
        }
    }

    // thread's W rows: k2 in [kq*32, kq*32+32), column j
    const uint4* wp  = (const uint4*)wbt + ((size_t)d * 128 + kq * 32) * 256 + j;
    const float* pxd = pxc + (size_t)d * 64 * B * G;

    // stage k2 0..8 into LDS (thread-private; written+read by same thread)
    #pragma unroll
    for (int r = 0; r < 9; r++)
        wst[(kq * 9 + r) * 256 + j] = wp[(size_t)r * 256];
    // resident k2 9..31 in named registers (23 x uint4 = 92 VGPR raw)
    uint4 wr0  = wp[9 * 256],  wr1  = wp[10 * 256], wr2  = wp[11 * 256];
    uint4 wr3  = wp[12 * 256], wr4  = wp[13 * 256], wr5  = wp[14 * 256];
    uint4 wr6  = wp[15 * 256], wr7  = wp[16 * 256], wr8  = wp[17 * 256];
    uint4 wr9  = wp[18 * 256], wr10 = wp[19 * 256], wr11 = wp[20 * 256];
    uint4 wr12 = wp[21 * 256], wr13 = wp[22 * 256], wr14 = wp[23 * 256];
    uint4 wr15 = wp[24 * 256], wr16 = wp[25 * 256], wr17 = wp[26 * 256];
    uint4 wr18 = wp[27 * 256], wr19 = wp[28 * 256], wr20 = wp[29 * 256];
    uint4 wr21 = wp[30 * 256], wr22 = wp[31 * 256];
    __syncthreads();

    int hlane = kq * 32 + (tid & 31);   // lanes 32..63 duplicate 0..31 (broadcast pair, free)
    int pendpos = -1;

    for (int t = t0; t < tend; t++) {
        int s = t - t0;

        // deferred hc_out store for step t-1: drains during this dot phase
        if (kq == 0 && pendpos >= 0)
            hc_out[((size_t)b * T + pendpos) * (2 * H) + d * H + j] = hreg;

        float p0, p1, p2, p3;
        if (kq == 0) {
            const float* pxs = pxd + ((size_t)s * B + b) * G;
            p0 = pxs[j];
            p1 = pxs[256 + j];
            p2 = pxs[512 + j];
            p3 = pxs[768 + j];
        }

        unsigned hlv = hh[hlane];       // one LDS b32/lane; rows via readlane

        float a0 = 0.f, a1 = 0.f, a2 = 0.f, a3 = 0.f;

        #define HROW(IDX) __builtin_amdgcn_readlane(hlv, IDX)
        #define DOT4(WV, IDX)                                          \
            { unsigned hu = HROW(IDX); half2v hx;                      \
              __builtin_memcpy(&hx, &hu, 4);                           \
              a0 = fdot2_(WV.x, hx, a0); a1 = fdot2_(WV.y, hx, a1);    \
              a2 = fdot2_(WV.z, hx, a2); a3 = fdot2_(WV.w, hx, a3); }

        // LDS-cached k2 0..8 (ds_reads issue early; compiler interleaves waits)
        #pragma unroll
        for (int r = 0; r < 9; r++) {
            uint4 wv = wst[(kq * 9 + r) * 256 + j];
            DOT4(wv, r)
        }
        // register-resident k2 9..31
        DOT4(wr0, 9)   DOT4(wr1, 10)  DOT4(wr2, 11)  DOT4(wr3, 12)
        DOT4(wr4, 13)  DOT4(wr5, 14)  DOT4(wr6, 15)  DOT4(wr7, 16)
        DOT4(wr8, 17)  DOT4(wr9, 18)  DOT4(wr10, 19) DOT4(wr11, 20)
        DOT4(wr12, 21) DOT4(wr13, 22) DOT4(wr14, 23) DOT4(wr15, 24)
        DOT4(wr16, 25) DOT4(wr17, 26) DOT4(wr18, 27) DOT4(wr19, 28)
        DOT4(wr20, 29) DOT4(wr21, 30) DOT4(wr22, 31)
        #undef DOT4
        #undef HROW

        if (kq > 0) part[(kq - 1) * 257 + j] = make_float4(a0, a1, a2, a3);
        __syncthreads();           // barrier 1: partials ready; hh reads done

        if (kq == 0) {
            __builtin_amdgcn_s_setprio(1);
            #pragma unroll
            for (int q = 0; q < 3; q++) {
                float4 qv = part[q * 257 + j];
                a0 += qv.x; a1 += qv.y; a2 += qv.z; a3 += qv.w;
            }
            a0 += p0; a1 += p1; a2 += p2; a3 += p3;

            float ig = sigmoid_fast_(a0), fg = sigmoid_fast_(a1), og = sigmoid_fast_(a3);
            c = fg * c + ig * tanh_fast_(a2);
            float h = og * tanh_fast_(c);
            hreg = h;
            hh16[j] = f2h_(h);      // per-thread b16 write (no shfl)
            pendpos = d ? (len - 1 - t) : t;
            __builtin_amdgcn_s_setprio(0);
        }
        __syncthreads();           // barrier 2: hh updated before next reads
    }

    if (kq == 0) {
        if (pendpos >= 0)
            hc_out[((size_t)b * T + pendpos) * (2 * H) + d * H + j] = hreg;
        cstate[((size_t)d * B + b) * H + j] = c;
        hbufg[j] = hreg;
    }
}

// ---------------- attention logits via MFMA --------------------------------
__global__ __launch_bounds__(256) void logits_kernel(const int* __restrict__ lengths,
                                                     const float* __restrict__ hc,
                                                     const uint4* __restrict__ ws1m,
                                                     const float* __restrict__ Ws2,
                                                     float* __restrict__ S) {
    __shared__ _Float16 A_s[64][520];   // 66560 B (pad: pitch 1040 B ~ bank+4)
    __shared__ _Float16 B_s[32][520];   // 33280 B

    int b = blockIdx.y, tt = blockIdx.x;
    int tid = threadIdx.x;
    int len = lengths[b];
    int t0 = tt * 64;

    int lane = tid & 63, wave = tid >> 6;
    int lr = lane & 15, lq = lane >> 4;
    int m0 = wave * 16;

    if (t0 >= len) {
        if (lr < HEADS) {
            #pragma unroll
            for (int rr = 0; rr < 4; rr++) {
                int t = t0 + m0 + lq * 4 + rr;
                S[((size_t)b * HEADS + lr) * T + t] = NEGINF;
            }
        }
        return;
    }

    // stage B: 32 rows x 512 f16 = 2048 uint4; 8 per thread
    {
        #pragma unroll
        for (int i = 0; i < 8; i++) {
            int u = tid + i * 256;
            int r = u >> 6, c8 = u & 63;
            *(uint4*)&B_s[r][c8 * 8] = ws1m[u];
        }
    }
    // stage A: 64 hc rows -> f16; thread = (row = tid>>2, quarter = tid&3)
    {
        int row = tid >> 2, q = tid & 3;
        int t = t0 + row;
        const float4* ep = (const float4*)(hc + ((size_t)b * T + t) * 512 + q * 128);
        #pragma unroll
        for (int c = 0; c < 16; c++) {
            float4 x0 = ep[2 * c];
            float4 x1 = ep[2 * c + 1];
            half8_ hv;
            hv[0] = (_Float16)x0.x; hv[1] = (_Float16)x0.y;
            hv[2] = (_Float16)x0.z; hv[3] = (_Float16)x0.w;
            hv[4] = (_Float16)x1.x; hv[5] = (_Float16)x1.y;
            hv[6] = (_Float16)x1.z; hv[7] = (_Float16)x1.w;
            *(half8_*)&A_s[row][q * 128 + c * 8] = hv;
        }
    }
    __syncthreads();

    f32x4 acc0 = {0.f, 0.f, 0.f, 0.f};   // n-tile 0: r = lr
    f32x4 acc1 = {0.f, 0.f, 0.f, 0.f};   // n-tile 1: r = lr + 16
    #pragma unroll
    for (int ks = 0; ks < 16; ks++) {
        int ka = ks * 32 + lq * 8;
        half8_ af  = *(const half8_*)&A_s[m0 + lr][ka];
        half8_ bf0 = *(const half8_*)&B_s[lr][ka];
        half8_ bf1 = *(const half8_*)&B_s[16 + lr][ka];
        acc0 = __builtin_amdgcn_mfma_f32_16x16x32_f16(af, bf0, acc0, 0, 0, 0);
        acc1 = __builtin_amdgcn_mfma_f32_16x16x32_f16(af, bf1, acc1, 0, 0, 0);
    }

    // W_s2 weights for this lane's two r-slots (r=lr, r=lr+16)
    float w2a[HEADS], w2b[HEADS];
    #pragma unroll
    for (int h = 0; h < HEADS; h++) {
        w2a[h] = Ws2[h * DA + lr];
        w2b[h] = (lr + 16 < DA) ? Ws2[h * DA + 16 + lr] : 0.f;
    }

    #pragma unroll
    for (int rr = 0; rr < 4; rr++) {
        float y0 = tanhf(acc0[rr]);
        float y1 = tanhf(acc1[rr]);
        int t = t0 + m0 + lq * 4 + rr;
        float sv[HEADS];
        #pragma unroll
        for (int h = 0; h < HEADS; h++) {
            float v = y0 * w2a[h] + y1 * w2b[h];
            v += __shfl_xor(v, 1, 16);
            v += __shfl_xor(v, 2, 16);
            v += __shfl_xor(v, 4, 16);
            v += __shfl_xor(v, 8, 16);
            sv[h] = v;
        }
        if (lr < HEADS) {
            S[((size_t)b * HEADS + lr) * T + t] = (t < len) ? sv[lr] : NEGINF;
        }
    }
}

// ---------------- masked softmax over T, in place ----------------
__global__ __launch_bounds__(256) void softmax_kernel(float* __restrict__ S) {
    int row = blockIdx.x;
    float* p = S + (size_t)row * T;
    int tid = threadIdx.x;
    int lane = tid & 63, wave = tid >> 6;
    __shared__ float rr[4], ss[4];

    float mx = NEGINF;
    #pragma unroll
    for (int i = 0; i < 2; i++) mx = fmaxf(mx, p[tid + i * 256]);
    for (int off = 32; off; off >>= 1) mx = fmaxf(mx, __shfl_xor(mx, off, 64));
    if (lane == 0) rr[wave] = mx;
    __syncthreads();
    mx = fmaxf(fmaxf(rr[0], rr[1]), fmaxf(rr[2], rr[3]));

    float e[2], sum = 0.f;
    #pragma unroll
    for (int i = 0; i < 2; i++) { e[i] = expf(p[tid + i * 256] - mx); sum += e[i]; }
    for (int off = 32; off; off >>= 1) sum += __shfl_xor(sum, off, 64);
    if (lane == 0) ss[wave] = sum;
    __syncthreads();
    sum = ss[0] + ss[1] + ss[2] + ss[3];
    float inv = 1.f / sum;
    #pragma unroll
    for (int i = 0; i < 2; i++) p[tid + i * 256] = e[i] * inv;
}

// ---------------- attnM partials: 8 t-chunks x 128 b ----------------------
__global__ __launch_bounds__(256) void attnM_part_kernel(const int* __restrict__ lengths,
                                                         const float* __restrict__ A,
                                                         const float* __restrict__ hc,
                                                         float* __restrict__ pm,
                                                         float* __restrict__ pp) {
    int tc = blockIdx.x, b = blockIdx.y, tid = threadIdx.x;
    int len = lengths[b];
    int t0 = tc * 64;
    int tend = min(t0 + 64, len);
    const float* Ab  = A + (size_t)b * HEADS * T;
    const float* hcb = hc + (size_t)b * T * (2 * H);
    float acc[HEADS][2];
    #pragma unroll
    for (int h = 0; h < HEADS; h++) { acc[h][0] = 0.f; acc[h][1] = 0.f; }
    float p[10];
    #pragma unroll
    for (int i = 0; i < 10; i++) p[i] = 0.f;

    for (int t = t0; t < tend; t++) {
        float v0 = hcb[(size_t)t * (2 * H) + tid];
        float v1 = hcb[(size_t)t * (2 * H) + H + tid];
        float a0 = Ab[t], a1 = Ab[T + t], a2 = Ab[2 * T + t], a3 = Ab[3 * T + t], a4 = Ab[4 * T + t];
        acc[0][0] += a0 * v0; acc[0][1] += a0 * v1;
        acc[1][0] += a1 * v0; acc[1][1] += a1 * v1;
        acc[2][0] += a2 * v0; acc[2][1] += a2 * v1;
        acc[3][0] += a3 * v0; acc[3][1] += a3 * v1;
        acc[4][0] += a4 * v0; acc[4][1] += a4 * v1;
        if ((t & 255) == tid) {
            p[0] += a0 * a1; p[1] += a0 * a2; p[2] += a0 * a3; p[3] += a0 * a4;
            p[4] += a1 * a2; p[5] += a1 * a3; p[6] += a1 * a4;
            p[7] += a2 * a3; p[8] += a2 * a4; p[9] += a3 * a4;
        }
    }
    size_t base = ((size_t)tc * B + b) * (HEADS * 2 * H);
    #pragma unroll
    for (int h = 0; h < HEADS; h++) {
        pm[base + h * (2 * H) + tid]     = acc[h][0];
        pm[base + h * (2 * H) + H + tid] = acc[h][1];
    }

    __shared__ float red[10][4];
    int lane = tid & 63, wave = tid >> 6;
    #pragma unroll
    for (int i = 0; i < 10; i++) {
        float v = p[i];
        for (int off = 32; off; off >>= 1) v += __shfl_xor(v, off, 64);
        if (lane == 0) red[i][wave] = v;
    }
    __syncthreads();
    if (tid < 10)
        pp[((size_t)tc * B + b) * 16 + tid] =
            red[tid][0] + red[tid][1] + red[tid][2] + red[tid][3];
}

// ---------------- reduce partials -> out + penal per b ---------------------
__global__ __launch_bounds__(256) void attnM_reduce_kernel(const float* __restrict__ pm,
                                                           const float* __restrict__ pp,
                                                           float* __restrict__ out,
                                                           float* __restrict__ part) {
    int b = blockIdx.x, tid = threadIdx.x;
    #pragma unroll
    for (int h = 0; h < HEADS; h++) {
        float a0 = 0.f, a1 = 0.f;
        #pragma unroll
        for (int tc = 0; tc < 8; tc++) {
            size_t base = ((size_t)tc * B + b) * (HEADS * 2 * H) + h * (2 * H);
            a0 += pm[base + tid];
            a1 += pm[base + H + tid];
        }
        out[(size_t)b * (HEADS * 2 * H) + h * (2 * H) + tid]     = a0;
        out[(size_t)b * (HEADS * 2 * H) + h * (2 * H) + H + tid] = a1;
    }
    __shared__ float sred[10];
    if (tid < 10) {
        float P = 0.f;
        #pragma unroll
        for (int tc = 0; tc < 8; tc++) P += pp[((size_t)tc * B + b) * 16 + tid];
        sred[tid] = 2.f * P * P;
    }
    __syncthreads();
    if (tid == 0) {
        float s = 0.f;
        #pragma unroll
        for (int i = 0; i < 10; i++) s += sred[i];
        part[b] = s;
    }
}

__global__ __launch_bounds__(128) void final_kernel(const float* __restrict__ part,
                                                    float* __restrict__ out) {
    int tid = threadIdx.x;
    float v = part[tid];
    for (int off = 32; off; off >>= 1) v += __shfl_xor(v, off, 64);
    __shared__ float r2[2];
    if ((tid & 63) == 0) r2[tid >> 6] = v;
    __syncthreads();
    if (tid == 0) out[(size_t)B * HEADS * 2 * H] = (r2[0] + r2[1]) * (1.f / (float)B);
}

// ---------------- host launcher ----------------
extern "C" void kernel_launch(void* const* d_in, const int* in_sizes, int n_in,
                              void* d_out, int out_size, void* d_ws, size_t ws_size,
                              hipStream_t stream) {
    const int*   word_ids = (const int*)d_in[0];
    const int*   lengths  = (const int*)d_in[1];
    const float* emb      = (const float*)d_in[2];
    const float* W_ih_f   = (const float*)d_in[3];
    const float* W_hh_f   = (const float*)d_in[4];
    const float* b_f      = (const float*)d_in[5];
    const float* W_ih_b   = (const float*)d_in[6];
    const float* W_hh_b   = (const float*)d_in[7];
    const float* b_b      = (const float*)d_in[8];
    const float* W_s1     = (const float*)d_in[9];
    const float* W_s2     = (const float*)d_in[10];
    float* out = (float*)d_out;

    char* ws = (char*)d_ws;
    unsigned short* wbt16 = (unsigned short*)(ws + WBT_OFF);
    unsigned*       wbt   = (unsigned*)(ws + WBT_OFF);
    unsigned short* wih16 = (unsigned short*)(ws + WIH_OFF);
    unsigned*       wihu  = (unsigned*)(ws + WIH_OFF);
    unsigned short* ws1m16 = (unsigned short*)(ws + WS1M_OFF);
    const uint4*    ws1m4  = (const uint4*)(ws + WS1M_OFF);
    float* pxc    = (float*)(ws + PX_OFF);
    float* hc     = (float*)(ws + HC_OFF);
    float* hbuf   = (float*)(ws + HBUF_OFF);
    float* cstate = (float*)(ws + CST_OFF);
    float* Abuf   = (float*)(ws + A_OFF);
    float* part   = (float*)(ws + PART_OFF);
    float* pm     = (float*)(ws + PM_OFF);   // overlays dead pxc
    float* pp     = (float*)(ws + PP_OFF);
    bool have_embh = (ws_size >= EMBH_END);
    unsigned short* embh16 = have_embh ? (unsigned short*)(ws + EMBH_OFF) : nullptr;
    const unsigned* embhu  = have_embh ? (const unsigned*)(ws + EMBH_OFF) : nullptr;

    prep_kernel<<<2080, 256, 0, stream>>>(W_hh_f, W_hh_b, W_ih_f, W_ih_b, W_s1, emb,
                                          wbt16, wih16, ws1m16, embh16);

    for (int c = 0; c < 8; c++) {
        proj_kernel<<<dim3(16, 128, 2), 256, 0, stream>>>(
            word_ids, lengths, emb, embhu, wihu, b_f, b_b, pxc, c);
        lstm6_kernel<<<dim3(128, 2), 1024, LSTM_LDS_BYTES, stream>>>(
            lengths, wbt, pxc, hc, hbuf, cstate, c);
    }

    logits_kernel<<<dim3(8, 128), 256, 0, stream>>>(lengths, hc, ws1m4, W_s2, Abuf);
    softmax_kernel<<<B * HEADS, 256, 0, stream>>>(Abuf);
    attnM_part_kernel<<<dim3(8, 128), 256, 0, stream>>>(lengths, Abuf, hc, pm, pp);
    attnM_reduce_kernel<<<B, 256, 0, stream>>>(pm, pp, out, part);
    final_kernel<<<1, 128, 0, stream>>>(part, out);
}